// Round 8
// baseline (2171.143 us; speedup 1.0000x reference)
//
#include <hip/hip_runtime.h>
#include <math.h>

#define BB 32
#define NN 1024
#define KNNK 20
#define PTS (BB*NN)   // 32768

typedef __attribute__((ext_vector_type(8)))  short short8;
typedef __attribute__((ext_vector_type(4)))  float f32x4;
typedef __attribute__((ext_vector_type(16))) float f32x16;

__device__ __forceinline__ float lrelu(float v){ return v >= 0.f ? v : 0.2f*v; }

__device__ __forceinline__ unsigned short f2b(float x){
    union { float f; unsigned u; } c; c.f = x;
    unsigned r = c.u + 0x7FFFu + ((c.u >> 16) & 1u);
    return (unsigned short)(r >> 16);
}

// ---------------- squared norms per point ----------------
__global__ void sq_kernel(const float* __restrict__ x, int stride, int C, float* __restrict__ xx){
    int pn = blockIdx.x*256 + threadIdx.x;
    if (pn >= PTS) return;
    const float* r = x + (size_t)pn*stride;
    float s = 0.f;
    for (int c = 0; c < C; ++c){ float v = r[c]; s = fmaf(v, v, s); }
    xx[pn] = s;
}

// ---------------- FUSED knn: distances in registers + radix top-k, no D buffer ----------------
// block = 16 rows of one batch, 4 waves x 4 rows. Lane holds slot s of each row:
// col = s*64+lane (s=0..15). D values bit-identical to prior rounds (same k-ascending fmaf
// chain, same 2a - xi - xj order); topk semantics identical (value desc, index asc).
template<int C>
__global__ void __launch_bounds__(256) knnf_kernel(const float* __restrict__ x, int stride,
                                                   const float* __restrict__ xx,
                                                   int* __restrict__ idxout){
    constexpr int KCH = (C >= 16) ? 16 : C;
    __shared__ float As[16][C+4];
    __shared__ float Bs[256][KCH+4];
    const int tid = threadIdx.x;
    const int w = tid >> 6, lane = tid & 63;
    const int bt = blockIdx.y;
    const int row0 = blockIdx.x * 16;
    const int wrow = w*4;
    const float* xb = x + (size_t)bt*NN*stride;

    if constexpr (C % 4 == 0){
        for (int i = tid; i < 16*(C/4); i += 256){
            int rr = i/(C/4), c4 = i%(C/4);
            *(float4*)&As[rr][c4*4] = *(const float4*)&xb[(size_t)(row0+rr)*stride + c4*4];
        }
    } else {
        for (int i = tid; i < 16*C; i += 256){
            int rr = i/C, c = i%C;
            As[rr][c] = xb[(size_t)(row0+rr)*stride + c];
        }
    }
    float xi[4];
    #pragma unroll
    for (int r=0;r<4;++r) xi[r] = xx[bt*NN + row0 + wrow + r];

    float v[4][16];
    for (int jp = 0; jp < 4; ++jp){
        #pragma unroll
        for (int r=0;r<4;++r)
            #pragma unroll
            for (int c=0;c<4;++c) v[r][jp*4+c] = 0.f;
        for (int kc = 0; kc < C; kc += KCH){
            __syncthreads();
            {   // stage B: col = tid, k in [kc, kc+KCH)
                const float* src = &xb[(size_t)(jp*256 + tid)*stride + kc];
                if constexpr (KCH % 4 == 0){
                    #pragma unroll
                    for (int k4 = 0; k4 < KCH/4; ++k4)
                        *(float4*)&Bs[tid][k4*4] = *(const float4*)&src[k4*4];
                } else {
                    #pragma unroll
                    for (int k = 0; k < KCH; ++k) Bs[tid][k] = src[k];
                }
            }
            __syncthreads();
            if constexpr (KCH % 4 == 0){
                #pragma unroll
                for (int k4 = 0; k4 < KCH/4; ++k4){
                    float4 a[4], bb[4];
                    #pragma unroll
                    for (int r=0;r<4;++r) a[r] = *(const float4*)&As[wrow+r][kc + k4*4];
                    #pragma unroll
                    for (int c=0;c<4;++c) bb[c] = *(const float4*)&Bs[c*64 + lane][k4*4];
                    #pragma unroll
                    for (int r=0;r<4;++r)
                        #pragma unroll
                        for (int c=0;c<4;++c){
                            float acc = v[r][jp*4+c];
                            acc = fmaf(a[r].x, bb[c].x, acc);
                            acc = fmaf(a[r].y, bb[c].y, acc);
                            acc = fmaf(a[r].z, bb[c].z, acc);
                            acc = fmaf(a[r].w, bb[c].w, acc);
                            v[r][jp*4+c] = acc;
                        }
                }
            } else {
                #pragma unroll
                for (int k = 0; k < KCH; ++k){
                    float a[4], bb[4];
                    #pragma unroll
                    for (int r=0;r<4;++r) a[r] = As[wrow+r][kc + k];
                    #pragma unroll
                    for (int c=0;c<4;++c) bb[c] = Bs[c*64 + lane][k];
                    #pragma unroll
                    for (int r=0;r<4;++r)
                        #pragma unroll
                        for (int c=0;c<4;++c)
                            v[r][jp*4+c] = fmaf(a[r], bb[c], v[r][jp*4+c]);
                }
            }
        }
        float xj[4];
        #pragma unroll
        for (int c=0;c<4;++c) xj[c] = xx[bt*NN + jp*256 + c*64 + lane];
        #pragma unroll
        for (int r=0;r<4;++r)
            #pragma unroll
            for (int c=0;c<4;++c)
                v[r][jp*4+c] = 2.f*v[r][jp*4+c] - xi[r] - xj[c];
    }

    // per-row radix top-k from registers (exact set, exact ties)
    const unsigned long long lt = (lane == 0) ? 0ull : ((~0ull) >> (64 - lane));
    #pragma unroll 1
    for (int r = 0; r < 4; ++r){
        unsigned u[16];
        #pragma unroll
        for (int i = 0; i < 16; ++i){
            unsigned bits = __float_as_uint(v[r][i]);
            u[i] = bits ^ ((bits & 0x80000000u) ? 0xFFFFFFFFu : 0x80000000u);
        }
        unsigned t = 0u;
        for (int bit = 31; bit >= 0; --bit){
            unsigned cand = t | (1u << bit);
            int cnt = 0;
            #pragma unroll
            for (int i = 0; i < 16; ++i)
                cnt += (int)__popcll(__ballot(u[i] >= cand));
            if (cnt >= KNNK) t = cand;
        }
        int* orow = idxout + ((size_t)bt*NN + row0 + wrow + r) * KNNK;
        int cbase = 0;
        #pragma unroll
        for (int i = 0; i < 16; ++i){
            bool g = (u[i] > t);
            unsigned long long mask = __ballot(g);
            if (g) orow[cbase + (int)__popcll(mask & lt)] = i*64 + lane;
            cbase += (int)__popcll(mask);
        }
        for (int i = 0; i < 16; ++i){
            if (cbase >= KNNK) break;
            bool e = (u[i] == t);
            unsigned long long mask = __ballot(e);
            int pos = cbase + (int)__popcll(mask & lt);
            if (e && pos < KNNK) orow[pos] = i*64 + lane;
            cbase += (int)__popcll(mask);
        }
    }
}

// ---------------- G GEMMs: G1 = X @ W[:, :C]^T ; Gd = X @ (W[:,C:]-W[:, :C])^T ----------------
template<int C, int O>
__global__ void __launch_bounds__(256) gemmG_kernel(const float* __restrict__ x, int stride,
                                                    const float* __restrict__ W,
                                                    float* __restrict__ G1, float* __restrict__ Gd){
    constexpr int KC = (C < 32 ? C : 32);
    __shared__ float Xl [KC][68];
    __shared__ float W1l[KC][68];
    __shared__ float W2l[KC][68];
    const int tid = threadIdx.x;
    const int r0 = blockIdx.x * 64;
    const int o0 = blockIdx.y * 64;
    const int rt = tid & 15, ct = tid >> 4;

    float a1[4][4] = {{0.f}}, a2[4][4] = {{0.f}};
    for (int kc = 0; kc < C; kc += KC){
        __syncthreads();
        for (int i = tid; i < KC*64; i += 256){
            int k = i % KC, rr = i / KC;
            Xl [k][rr] = x[(size_t)(r0+rr)*stride + kc + k];
            W1l[k][rr] = W[(size_t)(o0+rr)*(2*C) + kc + k];
            W2l[k][rr] = W[(size_t)(o0+rr)*(2*C) + C + kc + k];
        }
        __syncthreads();
        #pragma unroll
        for (int k = 0; k < KC; ++k){
            float4 xa = *(const float4*)&Xl [k][rt*4];
            float4 w1 = *(const float4*)&W1l[k][ct*4];
            float4 w2 = *(const float4*)&W2l[k][ct*4];
            float xv[4] = {xa.x, xa.y, xa.z, xa.w};
            #pragma unroll
            for (int i = 0; i < 4; ++i){
                a1[i][0] = fmaf(xv[i], w1.x, a1[i][0]);
                a1[i][1] = fmaf(xv[i], w1.y, a1[i][1]);
                a1[i][2] = fmaf(xv[i], w1.z, a1[i][2]);
                a1[i][3] = fmaf(xv[i], w1.w, a1[i][3]);
                a2[i][0] = fmaf(xv[i], w2.x, a2[i][0]);
                a2[i][1] = fmaf(xv[i], w2.y, a2[i][1]);
                a2[i][2] = fmaf(xv[i], w2.z, a2[i][2]);
                a2[i][3] = fmaf(xv[i], w2.w, a2[i][3]);
            }
        }
    }
    #pragma unroll
    for (int i = 0; i < 4; ++i){
        size_t row = (size_t)(r0 + rt*4 + i);
        float4 g1v = make_float4(a1[i][0], a1[i][1], a1[i][2], a1[i][3]);
        float4 gdv = make_float4(a2[i][0]-a1[i][0], a2[i][1]-a1[i][1],
                                 a2[i][2]-a1[i][2], a2[i][3]-a1[i][3]);
        *(float4*)&G1[row*O + o0 + ct*4] = g1v;
        *(float4*)&Gd[row*O + o0 + ct*4] = gdv;
    }
}

// ---------------- gather (float4): per (point, 4 cols) max/sum/sumsq over k ----------------
template<int O>
__global__ void __launch_bounds__(256) gather_kernel(const float* __restrict__ G1,
                                                     const float* __restrict__ Gd,
                                                     const int* __restrict__ idxg, int bgbase,
                                                     float* __restrict__ catslice,
                                                     float* __restrict__ stats){
    constexpr int OG = O/4;
    constexpr int PP = 256/OG;
    constexpr int NP = 16;
    __shared__ int nbs[NP][KNNK];
    const int tid = threadIdx.x;
    const int p0 = blockIdx.x * NP;
    for (int i = tid; i < NP*KNNK; i += 256){
        int pp = i / KNNK, kk = i - pp*KNNK;
        int pl = p0 + pp;
        nbs[pp][kk] = ((pl >> 10) << 10) + idxg[(size_t)(bgbase + pl)*KNNK + kk];
    }
    __syncthreads();
    const int o4 = (tid % OG)*4;
    const int pq = tid / OG;
    float S1[4] = {0.f,0.f,0.f,0.f}, S2[4] = {0.f,0.f,0.f,0.f};
    for (int pp = pq; pp < NP; pp += PP){
        int pl = p0 + pp;
        float4 dv = *(const float4*)&Gd[(size_t)pl*O + o4];
        float d[4] = {dv.x, dv.y, dv.z, dv.w};
        float mx[4] = {-INFINITY,-INFINITY,-INFINITY,-INFINITY};
        float ls[4] = {0.f,0.f,0.f,0.f}, lq[4] = {0.f,0.f,0.f,0.f};
        #pragma unroll
        for (int kk = 0; kk < KNNK; ++kk){
            float4 gv = *(const float4*)&G1[(size_t)nbs[pp][kk]*O + o4];
            float ga[4] = {gv.x, gv.y, gv.z, gv.w};
            #pragma unroll
            for (int c = 0; c < 4; ++c){
                mx[c] = fmaxf(mx[c], ga[c]);
                ls[c] += ga[c];
                lq[c] = fmaf(ga[c], ga[c], lq[c]);
            }
        }
        float4 outv;
        float* op = &outv.x;
        #pragma unroll
        for (int c = 0; c < 4; ++c){
            S1[c] += ls[c] + 20.f*d[c];
            S2[c] += lq[c] + 2.f*d[c]*ls[c] + 20.f*d[c]*d[c];
            op[c] = mx[c] + d[c];
        }
        *(float4*)&catslice[(size_t)(bgbase + pl)*512 + o4] = outv;
    }
    int rep = blockIdx.x & 63;
    #pragma unroll
    for (int c = 0; c < 4; ++c){
        atomicAdd(&stats[rep*2*O + o4 + c],     S1[c]);
        atomicAdd(&stats[rep*2*O + O + o4 + c], S2[c]);
    }
}

// ---------------- finalize BN stats ----------------
__global__ void fin_kernel(const float* __restrict__ stats, int O, float cnt,
                           float* __restrict__ mean, float* __restrict__ invstd){
    int o = threadIdx.x;
    if (o >= O) return;
    float s1 = 0.f, s2 = 0.f;
    for (int r = 0; r < 64; ++r){
        s1 += stats[r*2*O + o];
        s2 += stats[r*2*O + O + o];
    }
    float m = s1 / cnt;
    float v = s2 / cnt - m*m;
    mean[o] = m;
    invstd[o] = rsqrtf(v + 1e-5f);
}

// ---------------- apply BN+LReLU in place on cat slice ----------------
template<int O>
__global__ void apply_kernel(float* __restrict__ catslice,
                             const float* __restrict__ mean, const float* __restrict__ invstd,
                             const float* __restrict__ g, const float* __restrict__ bt){
    int i = blockIdx.x*256 + threadIdx.x;
    int pn = i / O, o = i - pn*O;
    float* p = &catslice[(size_t)pn*512 + o];
    float hn = (*p - mean[o]) * invstd[o] * g[o] + bt[o];
    *p = lrelu(hn);
}

// ---------------- fp32 -> bf16 conversion (4 elems/thread) ----------------
__global__ void tob16_kernel(const float* __restrict__ src, unsigned short* __restrict__ dst, int n4){
    int i = blockIdx.x*256 + threadIdx.x;
    if (i >= n4) return;
    float4 v = *(const float4*)&src[(size_t)i*4];
    ushort4 o;
    o.x = f2b(v.x); o.y = f2b(v.y); o.z = f2b(v.z); o.w = f2b(v.w);
    *(ushort4*)&dst[(size_t)i*4] = o;
}

// ---------------- layer 5 MFMA: 32x32x16 frags, 64x64/wave, 128x128/block ----------------
__global__ void __launch_bounds__(256) l5m_kernel(const unsigned short* __restrict__ Am,
                                                  const unsigned short* __restrict__ Bm,
                                                  float* __restrict__ pmax,
                                                  float* __restrict__ psum,
                                                  float* __restrict__ psq){
    __shared__ __align__(16) unsigned short As[128][64];
    __shared__ __align__(16) unsigned short Bs[128][64];
    const int tid = threadIdx.x;
    const int r0 = blockIdx.x * 128;
    const int o0 = blockIdx.y * 128;
    const int w = tid >> 6, lane = tid & 63;
    const int m32 = lane & 31, kh = lane >> 5;
    const int wm = (w & 1) * 64;
    const int wn = (w >> 1) * 64;

    f32x16 acc[2][2];
    #pragma unroll
    for (int i=0;i<2;++i)
        #pragma unroll
        for (int j=0;j<2;++j)
            #pragma unroll
            for (int r=0;r<16;++r) acc[i][j][r] = 0.f;

    for (int kc = 0; kc < 512; kc += 64){
        __syncthreads();
        #pragma unroll
        for (int t = 0; t < 4; ++t){
            int i = tid + t*256;
            int rr = i >> 3, ch = i & 7;
            int sl = ch ^ (rr & 7);
            *(uint4*)&As[rr][sl*8] = *(const uint4*)&Am[(size_t)(r0+rr)*512 + kc + ch*8];
            *(uint4*)&Bs[rr][sl*8] = *(const uint4*)&Bm[(size_t)(o0+rr)*512 + kc + ch*8];
        }
        __syncthreads();
        #pragma unroll
        for (int q = 0; q < 4; ++q){
            int lk = q*2 + kh;
            short8 a[2], bfr[2];
            #pragma unroll
            for (int mb = 0; mb < 2; ++mb){
                int rA = wm + mb*32 + m32;
                a[mb] = *(const short8*)&As[rA][(lk ^ (rA & 7))*8];
            }
            #pragma unroll
            for (int nb = 0; nb < 2; ++nb){
                int rB = wn + nb*32 + m32;
                bfr[nb] = *(const short8*)&Bs[rB][(lk ^ (rB & 7))*8];
            }
            #pragma unroll
            for (int mb = 0; mb < 2; ++mb)
                #pragma unroll
                for (int nb = 0; nb < 2; ++nb)
                    acc[mb][nb] = __builtin_amdgcn_mfma_f32_32x32x16_bf16(a[mb], bfr[nb], acc[mb][nb], 0, 0, 0);
        }
    }
    __syncthreads();
    float* red = (float*)&As[0][0];
    #pragma unroll
    for (int nb = 0; nb < 2; ++nb){
        float mx = -INFINITY, s1 = 0.f, s2 = 0.f;
        #pragma unroll
        for (int mb = 0; mb < 2; ++mb)
            #pragma unroll
            for (int r = 0; r < 16; ++r){
                float v = acc[mb][nb][r];
                mx = fmaxf(mx, v); s1 += v; s2 = fmaf(v, v, s2);
            }
        mx = fmaxf(mx, __shfl_xor(mx, 32));
        s1 += __shfl_xor(s1, 32);
        s2 += __shfl_xor(s2, 32);
        if (lane < 32){
            int col = wn + nb*32 + m32;
            float* p = red + ((size_t)(w & 1) * 128 + col) * 3;
            p[0] = mx; p[1] = s1; p[2] = s2;
        }
    }
    __syncthreads();
    if (tid < 128){
        const float* p0 = red + (size_t)tid*3;
        const float* p1 = red + (size_t)(128 + tid)*3;
        float mx = fmaxf(p0[0], p1[0]);
        float s1 = p0[1] + p1[1];
        float s2 = p0[2] + p1[2];
        size_t pi = (size_t)blockIdx.x*1024 + o0 + tid;
        pmax[pi] = mx; psum[pi] = s1; psq[pi] = s2;
    }
}

__global__ void fin5_kernel(const float* __restrict__ pmax, const float* __restrict__ psum,
                            const float* __restrict__ psq,
                            const float* __restrict__ g, const float* __restrict__ bt,
                            float* __restrict__ out){
    int o = blockIdx.x*256 + threadIdx.x; // 1024 total
    float s1 = 0.f, s2 = 0.f;
    for (int r = 0; r < 256; ++r){
        s1 += psum[(size_t)r*1024 + o];
        s2 += psq [(size_t)r*1024 + o];
    }
    float m  = s1 / 32768.f;
    float v  = s2 / 32768.f - m*m;
    float is = rsqrtf(v + 1e-5f);
    float gg = g[o], bb2 = bt[o];
    for (int b = 0; b < 32; ++b){
        float mx = -INFINITY;
        #pragma unroll
        for (int ns = 0; ns < 8; ++ns) mx = fmaxf(mx, pmax[((size_t)b*8 + ns)*1024 + o]);
        float hn = (mx - m) * is * gg + bb2;
        out[(size_t)b*1024 + o] = lrelu(hn);
    }
}

extern "C" void kernel_launch(void* const* d_in, const int* in_sizes, int n_in,
                              void* d_out, int out_size, void* d_ws, size_t ws_size,
                              hipStream_t stream) {
    (void)in_sizes; (void)n_in; (void)out_size;
    const float* x  = (const float*)d_in[0];
    const float* W1 = (const float*)d_in[1];  const float* g1 = (const float*)d_in[2];  const float* b1 = (const float*)d_in[3];
    const float* W2 = (const float*)d_in[4];  const float* g2 = (const float*)d_in[5];  const float* b2 = (const float*)d_in[6];
    const float* W3 = (const float*)d_in[7];  const float* g3 = (const float*)d_in[8];  const float* b3 = (const float*)d_in[9];
    const float* W4 = (const float*)d_in[10]; const float* g4 = (const float*)d_in[11]; const float* b4 = (const float*)d_in[12];
    const float* W5 = (const float*)d_in[13]; const float* g5 = (const float*)d_in[14]; const float* b5 = (const float*)d_in[15];
    float* out = (float*)d_out;

    const size_t fixedBytes = (size_t)PTS*512*4 + (size_t)PTS*KNNK*4 + (size_t)PTS*4
                            + (size_t)64*2*256*4 + 2048*4 + 3*(size_t)256*1024*4
                            + (size_t)1024*512*2;            // ~74.2 MB
    const bool bigG = (ws_size >= fixedBytes + (size_t)64*1024*1024);
    const size_t Rbytes = bigG ? (size_t)64*1024*1024 : (size_t)32*1024*1024;

    char* wsp = (char*)d_ws;
    float* cat    = (float*)wsp; wsp += (size_t)PTS*512*4;
    char*  R      = wsp;         wsp += Rbytes;
    int*   idx    = (int*)  wsp; wsp += (size_t)PTS*KNNK*4;
    float* xx     = (float*)wsp; wsp += (size_t)PTS*4;
    float* stats  = (float*)wsp; wsp += (size_t)64*2*256*4;
    float* mean   = (float*)wsp; wsp += 1024*4;
    float* invstd = (float*)wsp; wsp += 1024*4;
    float* pmax   = (float*)wsp; wsp += (size_t)256*1024*4;
    float* psum   = (float*)wsp; wsp += (size_t)256*1024*4;
    float* psq    = (float*)wsp; wsp += (size_t)256*1024*4;
    unsigned short* W5b = (unsigned short*)wsp; wsp += (size_t)1024*512*2;

    float* G1   = (float*)R;
    float* GdS  = (float*)(R + (size_t)16*1024*1024);   // small-mode Gd
    float* GdB  = (float*)(R + (size_t)32*1024*1024);   // big-mode full-PTS O=256 Gd
    unsigned short* catB = (unsigned short*)R;

    const float cntE = (float)(PTS*KNNK);

    // ---- Layer 1: C=3 -> O=64 ----
    sq_kernel<<<PTS/256, 256, 0, stream>>>(x, 3, 3, xx);
    knnf_kernel<3><<<dim3(64,32), 256, 0, stream>>>(x, 3, xx, idx);
    hipMemsetAsync(stats, 0, 64*2*256*4, stream);
    gemmG_kernel<3,64><<<dim3(512,1), 256, 0, stream>>>(x, 3, W1, G1, GdS);
    gather_kernel<64><<<2048, 256, 0, stream>>>(G1, GdS, idx, 0, cat + 0, stats);
    fin_kernel<<<1, 64, 0, stream>>>(stats, 64, cntE, mean, invstd);
    apply_kernel<64><<<PTS*64/256, 256, 0, stream>>>(cat + 0, mean, invstd, g1, b1);

    // ---- Layer 2: C=64 -> O=64 ----
    sq_kernel<<<PTS/256, 256, 0, stream>>>(cat + 0, 512, 64, xx);
    knnf_kernel<64><<<dim3(64,32), 256, 0, stream>>>(cat + 0, 512, xx, idx);
    hipMemsetAsync(stats, 0, 64*2*256*4, stream);
    gemmG_kernel<64,64><<<dim3(512,1), 256, 0, stream>>>(cat + 0, 512, W2, G1, GdS);
    gather_kernel<64><<<2048, 256, 0, stream>>>(G1, GdS, idx, 0, cat + 64, stats);
    fin_kernel<<<1, 64, 0, stream>>>(stats, 64, cntE, mean, invstd);
    apply_kernel<64><<<PTS*64/256, 256, 0, stream>>>(cat + 64, mean, invstd, g2, b2);

    // ---- Layer 3: C=64 -> O=128 ----
    sq_kernel<<<PTS/256, 256, 0, stream>>>(cat + 64, 512, 64, xx);
    knnf_kernel<64><<<dim3(64,32), 256, 0, stream>>>(cat + 64, 512, xx, idx);
    hipMemsetAsync(stats, 0, 64*2*256*4, stream);
    gemmG_kernel<64,128><<<dim3(512,2), 256, 0, stream>>>(cat + 64, 512, W3, G1, GdS);
    gather_kernel<128><<<2048, 256, 0, stream>>>(G1, GdS, idx, 0, cat + 128, stats);
    fin_kernel<<<1, 128, 0, stream>>>(stats, 128, cntE, mean, invstd);
    apply_kernel<128><<<PTS*128/256, 256, 0, stream>>>(cat + 128, mean, invstd, g3, b3);

    // ---- Layer 4: C=128 -> O=256 ----
    sq_kernel<<<PTS/256, 256, 0, stream>>>(cat + 128, 512, 128, xx);
    knnf_kernel<128><<<dim3(64,32), 256, 0, stream>>>(cat + 128, 512, xx, idx);
    hipMemsetAsync(stats, 0, 64*2*256*4, stream);
    if (bigG){
        gemmG_kernel<128,256><<<dim3(512,4), 256, 0, stream>>>(cat + 128, 512, W4, G1, GdB);
        gather_kernel<256><<<2048, 256, 0, stream>>>(G1, GdB, idx, 0, cat + 256, stats);
    } else {
        for (int bg = 0; bg < 4; ++bg){
            gemmG_kernel<128,256><<<dim3(128,4), 256, 0, stream>>>(cat + 128 + (size_t)bg*8192*512, 512, W4, G1, GdS);
            gather_kernel<256><<<512, 256, 0, stream>>>(G1, GdS, idx, bg*8192, cat + 256, stats);
        }
    }
    fin_kernel<<<1, 256, 0, stream>>>(stats, 256, cntE, mean, invstd);
    apply_kernel<256><<<PTS*256/256, 256, 0, stream>>>(cat + 256, mean, invstd, g4, b4);

    // ---- Layer 5: bf16 MFMA GEMM with fused max/stats ----
    tob16_kernel<<<PTS*512/4/256, 256, 0, stream>>>(cat, catB, PTS*512/4);
    tob16_kernel<<<1024*512/4/256, 256, 0, stream>>>(W5, W5b, 1024*512/4);
    l5m_kernel<<<dim3(256, 8), 256, 0, stream>>>(catB, W5b, pmax, psum, psq);
    fin5_kernel<<<4, 256, 0, stream>>>(pmax, psum, psq, g5, b5, out);
}

// Round 9
// 2096.705 us; speedup vs baseline: 1.0355x; 1.0355x over previous
//
#include <hip/hip_runtime.h>
#include <math.h>

#define BB 32
#define NN 1024
#define KNNK 20
#define PTS (BB*NN)   // 32768

typedef __attribute__((ext_vector_type(8)))  short short8;
typedef __attribute__((ext_vector_type(4)))  float f32x4;
typedef __attribute__((ext_vector_type(16))) float f32x16;

__device__ __forceinline__ float lrelu(float v){ return v >= 0.f ? v : 0.2f*v; }

__device__ __forceinline__ unsigned short f2b(float x){
    union { float f; unsigned u; } c; c.f = x;
    unsigned r = c.u + 0x7FFFu + ((c.u >> 16) & 1u);
    return (unsigned short)(r >> 16);
}

// ---------------- squared norms per point ----------------
__global__ void sq_kernel(const float* __restrict__ x, int stride, int C, float* __restrict__ xx){
    int pn = blockIdx.x*256 + threadIdx.x;
    if (pn >= PTS) return;
    const float* r = x + (size_t)pn*stride;
    float s = 0.f;
    for (int c = 0; c < C; ++c){ float v = r[c]; s = fmaf(v, v, s); }
    xx[pn] = s;
}

// ---------------- FUSED knn: distances in registers + radix top-k, no D buffer ----------------
// block = 16 rows of one batch, 4 waves x 4 rows. Lane holds slot s of each row:
// col = s*64+lane (s=0..15). ALL loops touching v[][] are fully unrolled -> static
// register indexing (R8's scratch-spill bug: dynamic jp/r indexing put v in scratch,
// 704 MB/dispatch spill traffic). D values bit-identical (k-ascending fmaf chain,
// 2a - xi - xj order); topk semantics identical (value desc, index asc).
template<int C>
__global__ void __launch_bounds__(256) knnf_kernel(const float* __restrict__ x, int stride,
                                                   const float* __restrict__ xx,
                                                   int* __restrict__ idxout){
    constexpr int KCH = (C >= 16) ? 16 : C;
    __shared__ float As[16][C+4];
    __shared__ float Bs[256][KCH+4];
    const int tid = threadIdx.x;
    const int w = tid >> 6, lane = tid & 63;
    const int bt = blockIdx.y;
    const int row0 = blockIdx.x * 16;
    const int wrow = w*4;
    const float* xb = x + (size_t)bt*NN*stride;

    if constexpr (C % 4 == 0){
        for (int i = tid; i < 16*(C/4); i += 256){
            int rr = i/(C/4), c4 = i%(C/4);
            *(float4*)&As[rr][c4*4] = *(const float4*)&xb[(size_t)(row0+rr)*stride + c4*4];
        }
    } else {
        for (int i = tid; i < 16*C; i += 256){
            int rr = i/C, c = i%C;
            As[rr][c] = xb[(size_t)(row0+rr)*stride + c];
        }
    }
    float xi[4];
    #pragma unroll
    for (int r=0;r<4;++r) xi[r] = xx[bt*NN + row0 + wrow + r];

    float v[4][16];
    #pragma unroll
    for (int jp = 0; jp < 4; ++jp){
        #pragma unroll
        for (int r=0;r<4;++r)
            #pragma unroll
            for (int c=0;c<4;++c) v[r][jp*4+c] = 0.f;
        for (int kc = 0; kc < C; kc += KCH){
            __syncthreads();
            {   // stage B: col = jp*256+tid, k in [kc, kc+KCH)
                const float* src = &xb[(size_t)(jp*256 + tid)*stride + kc];
                if constexpr (KCH % 4 == 0){
                    #pragma unroll
                    for (int k4 = 0; k4 < KCH/4; ++k4)
                        *(float4*)&Bs[tid][k4*4] = *(const float4*)&src[k4*4];
                } else {
                    #pragma unroll
                    for (int k = 0; k < KCH; ++k) Bs[tid][k] = src[k];
                }
            }
            __syncthreads();
            if constexpr (KCH % 4 == 0){
                #pragma unroll
                for (int k4 = 0; k4 < KCH/4; ++k4){
                    float4 a[4], bb[4];
                    #pragma unroll
                    for (int r=0;r<4;++r) a[r] = *(const float4*)&As[wrow+r][kc + k4*4];
                    #pragma unroll
                    for (int c=0;c<4;++c) bb[c] = *(const float4*)&Bs[c*64 + lane][k4*4];
                    #pragma unroll
                    for (int r=0;r<4;++r)
                        #pragma unroll
                        for (int c=0;c<4;++c){
                            float acc = v[r][jp*4+c];
                            acc = fmaf(a[r].x, bb[c].x, acc);
                            acc = fmaf(a[r].y, bb[c].y, acc);
                            acc = fmaf(a[r].z, bb[c].z, acc);
                            acc = fmaf(a[r].w, bb[c].w, acc);
                            v[r][jp*4+c] = acc;
                        }
                }
            } else {
                #pragma unroll
                for (int k = 0; k < KCH; ++k){
                    float a[4], bb[4];
                    #pragma unroll
                    for (int r=0;r<4;++r) a[r] = As[wrow+r][kc + k];
                    #pragma unroll
                    for (int c=0;c<4;++c) bb[c] = Bs[c*64 + lane][k];
                    #pragma unroll
                    for (int r=0;r<4;++r)
                        #pragma unroll
                        for (int c=0;c<4;++c)
                            v[r][jp*4+c] = fmaf(a[r], bb[c], v[r][jp*4+c]);
                }
            }
        }
        float xj[4];
        #pragma unroll
        for (int c=0;c<4;++c) xj[c] = xx[bt*NN + jp*256 + c*64 + lane];
        #pragma unroll
        for (int r=0;r<4;++r)
            #pragma unroll
            for (int c=0;c<4;++c)
                v[r][jp*4+c] = 2.f*v[r][jp*4+c] - xi[r] - xj[c];
    }

    // per-row radix top-k from registers (exact set, exact ties); r fully unrolled
    const unsigned long long lt = (lane == 0) ? 0ull : ((~0ull) >> (64 - lane));
    #pragma unroll
    for (int r = 0; r < 4; ++r){
        unsigned u[16];
        #pragma unroll
        for (int i = 0; i < 16; ++i){
            unsigned bits = __float_as_uint(v[r][i]);
            u[i] = bits ^ ((bits & 0x80000000u) ? 0xFFFFFFFFu : 0x80000000u);
        }
        unsigned t = 0u;
        for (int bit = 31; bit >= 0; --bit){
            unsigned cand = t | (1u << bit);
            int cnt = 0;
            #pragma unroll
            for (int i = 0; i < 16; ++i)
                cnt += (int)__popcll(__ballot(u[i] >= cand));
            if (cnt >= KNNK) t = cand;
        }
        int* orow = idxout + ((size_t)bt*NN + row0 + wrow + r) * KNNK;
        int cbase = 0;
        #pragma unroll
        for (int i = 0; i < 16; ++i){
            bool g = (u[i] > t);
            unsigned long long mask = __ballot(g);
            if (g) orow[cbase + (int)__popcll(mask & lt)] = i*64 + lane;
            cbase += (int)__popcll(mask);
        }
        #pragma unroll
        for (int i = 0; i < 16; ++i){
            if (cbase >= KNNK) break;
            bool e = (u[i] == t);
            unsigned long long mask = __ballot(e);
            int pos = cbase + (int)__popcll(mask & lt);
            if (e && pos < KNNK) orow[pos] = i*64 + lane;
            cbase += (int)__popcll(mask);
        }
    }
}

// ---------------- G GEMMs: G1 = X @ W[:, :C]^T ; Gd = X @ (W[:,C:]-W[:, :C])^T ----------------
template<int C, int O>
__global__ void __launch_bounds__(256) gemmG_kernel(const float* __restrict__ x, int stride,
                                                    const float* __restrict__ W,
                                                    float* __restrict__ G1, float* __restrict__ Gd){
    constexpr int KC = (C < 32 ? C : 32);
    __shared__ float Xl [KC][68];
    __shared__ float W1l[KC][68];
    __shared__ float W2l[KC][68];
    const int tid = threadIdx.x;
    const int r0 = blockIdx.x * 64;
    const int o0 = blockIdx.y * 64;
    const int rt = tid & 15, ct = tid >> 4;

    float a1[4][4] = {{0.f}}, a2[4][4] = {{0.f}};
    for (int kc = 0; kc < C; kc += KC){
        __syncthreads();
        for (int i = tid; i < KC*64; i += 256){
            int k = i % KC, rr = i / KC;
            Xl [k][rr] = x[(size_t)(r0+rr)*stride + kc + k];
            W1l[k][rr] = W[(size_t)(o0+rr)*(2*C) + kc + k];
            W2l[k][rr] = W[(size_t)(o0+rr)*(2*C) + C + kc + k];
        }
        __syncthreads();
        #pragma unroll
        for (int k = 0; k < KC; ++k){
            float4 xa = *(const float4*)&Xl [k][rt*4];
            float4 w1 = *(const float4*)&W1l[k][ct*4];
            float4 w2 = *(const float4*)&W2l[k][ct*4];
            float xv[4] = {xa.x, xa.y, xa.z, xa.w};
            #pragma unroll
            for (int i = 0; i < 4; ++i){
                a1[i][0] = fmaf(xv[i], w1.x, a1[i][0]);
                a1[i][1] = fmaf(xv[i], w1.y, a1[i][1]);
                a1[i][2] = fmaf(xv[i], w1.z, a1[i][2]);
                a1[i][3] = fmaf(xv[i], w1.w, a1[i][3]);
                a2[i][0] = fmaf(xv[i], w2.x, a2[i][0]);
                a2[i][1] = fmaf(xv[i], w2.y, a2[i][1]);
                a2[i][2] = fmaf(xv[i], w2.z, a2[i][2]);
                a2[i][3] = fmaf(xv[i], w2.w, a2[i][3]);
            }
        }
    }
    #pragma unroll
    for (int i = 0; i < 4; ++i){
        size_t row = (size_t)(r0 + rt*4 + i);
        float4 g1v = make_float4(a1[i][0], a1[i][1], a1[i][2], a1[i][3]);
        float4 gdv = make_float4(a2[i][0]-a1[i][0], a2[i][1]-a1[i][1],
                                 a2[i][2]-a1[i][2], a2[i][3]-a1[i][3]);
        *(float4*)&G1[row*O + o0 + ct*4] = g1v;
        *(float4*)&Gd[row*O + o0 + ct*4] = gdv;
    }
}

// ---------------- gather (float4): per (point, 4 cols) max/sum/sumsq over k ----------------
template<int O>
__global__ void __launch_bounds__(256) gather_kernel(const float* __restrict__ G1,
                                                     const float* __restrict__ Gd,
                                                     const int* __restrict__ idxg, int bgbase,
                                                     float* __restrict__ catslice,
                                                     float* __restrict__ stats){
    constexpr int OG = O/4;
    constexpr int PP = 256/OG;
    constexpr int NP = 16;
    __shared__ int nbs[NP][KNNK];
    const int tid = threadIdx.x;
    const int p0 = blockIdx.x * NP;
    for (int i = tid; i < NP*KNNK; i += 256){
        int pp = i / KNNK, kk = i - pp*KNNK;
        int pl = p0 + pp;
        nbs[pp][kk] = ((pl >> 10) << 10) + idxg[(size_t)(bgbase + pl)*KNNK + kk];
    }
    __syncthreads();
    const int o4 = (tid % OG)*4;
    const int pq = tid / OG;
    float S1[4] = {0.f,0.f,0.f,0.f}, S2[4] = {0.f,0.f,0.f,0.f};
    for (int pp = pq; pp < NP; pp += PP){
        int pl = p0 + pp;
        float4 dv = *(const float4*)&Gd[(size_t)pl*O + o4];
        float d[4] = {dv.x, dv.y, dv.z, dv.w};
        float mx[4] = {-INFINITY,-INFINITY,-INFINITY,-INFINITY};
        float ls[4] = {0.f,0.f,0.f,0.f}, lq[4] = {0.f,0.f,0.f,0.f};
        #pragma unroll
        for (int kk = 0; kk < KNNK; ++kk){
            float4 gv = *(const float4*)&G1[(size_t)nbs[pp][kk]*O + o4];
            float ga[4] = {gv.x, gv.y, gv.z, gv.w};
            #pragma unroll
            for (int c = 0; c < 4; ++c){
                mx[c] = fmaxf(mx[c], ga[c]);
                ls[c] += ga[c];
                lq[c] = fmaf(ga[c], ga[c], lq[c]);
            }
        }
        float4 outv;
        float* op = &outv.x;
        #pragma unroll
        for (int c = 0; c < 4; ++c){
            S1[c] += ls[c] + 20.f*d[c];
            S2[c] += lq[c] + 2.f*d[c]*ls[c] + 20.f*d[c]*d[c];
            op[c] = mx[c] + d[c];
        }
        *(float4*)&catslice[(size_t)(bgbase + pl)*512 + o4] = outv;
    }
    int rep = blockIdx.x & 63;
    #pragma unroll
    for (int c = 0; c < 4; ++c){
        atomicAdd(&stats[rep*2*O + o4 + c],     S1[c]);
        atomicAdd(&stats[rep*2*O + O + o4 + c], S2[c]);
    }
}

// ---------------- finalize BN stats ----------------
__global__ void fin_kernel(const float* __restrict__ stats, int O, float cnt,
                           float* __restrict__ mean, float* __restrict__ invstd){
    int o = threadIdx.x;
    if (o >= O) return;
    float s1 = 0.f, s2 = 0.f;
    for (int r = 0; r < 64; ++r){
        s1 += stats[r*2*O + o];
        s2 += stats[r*2*O + O + o];
    }
    float m = s1 / cnt;
    float v = s2 / cnt - m*m;
    mean[o] = m;
    invstd[o] = rsqrtf(v + 1e-5f);
}

// ---------------- apply BN+LReLU in place on cat slice ----------------
template<int O>
__global__ void apply_kernel(float* __restrict__ catslice,
                             const float* __restrict__ mean, const float* __restrict__ invstd,
                             const float* __restrict__ g, const float* __restrict__ bt){
    int i = blockIdx.x*256 + threadIdx.x;
    int pn = i / O, o = i - pn*O;
    float* p = &catslice[(size_t)pn*512 + o];
    float hn = (*p - mean[o]) * invstd[o] * g[o] + bt[o];
    *p = lrelu(hn);
}

// ---------------- fp32 -> bf16 conversion (4 elems/thread) ----------------
__global__ void tob16_kernel(const float* __restrict__ src, unsigned short* __restrict__ dst, int n4){
    int i = blockIdx.x*256 + threadIdx.x;
    if (i >= n4) return;
    float4 v = *(const float4*)&src[(size_t)i*4];
    ushort4 o;
    o.x = f2b(v.x); o.y = f2b(v.y); o.z = f2b(v.z); o.w = f2b(v.w);
    *(ushort4*)&dst[(size_t)i*4] = o;
}

// ---------------- layer 5 MFMA: 32x32x16 frags, 64x64/wave, 128x128/block ----------------
__global__ void __launch_bounds__(256) l5m_kernel(const unsigned short* __restrict__ Am,
                                                  const unsigned short* __restrict__ Bm,
                                                  float* __restrict__ pmax,
                                                  float* __restrict__ psum,
                                                  float* __restrict__ psq){
    __shared__ __align__(16) unsigned short As[128][64];
    __shared__ __align__(16) unsigned short Bs[128][64];
    const int tid = threadIdx.x;
    const int r0 = blockIdx.x * 128;
    const int o0 = blockIdx.y * 128;
    const int w = tid >> 6, lane = tid & 63;
    const int m32 = lane & 31, kh = lane >> 5;
    const int wm = (w & 1) * 64;
    const int wn = (w >> 1) * 64;

    f32x16 acc[2][2];
    #pragma unroll
    for (int i=0;i<2;++i)
        #pragma unroll
        for (int j=0;j<2;++j)
            #pragma unroll
            for (int r=0;r<16;++r) acc[i][j][r] = 0.f;

    for (int kc = 0; kc < 512; kc += 64){
        __syncthreads();
        #pragma unroll
        for (int t = 0; t < 4; ++t){
            int i = tid + t*256;
            int rr = i >> 3, ch = i & 7;
            int sl = ch ^ (rr & 7);
            *(uint4*)&As[rr][sl*8] = *(const uint4*)&Am[(size_t)(r0+rr)*512 + kc + ch*8];
            *(uint4*)&Bs[rr][sl*8] = *(const uint4*)&Bm[(size_t)(o0+rr)*512 + kc + ch*8];
        }
        __syncthreads();
        #pragma unroll
        for (int q = 0; q < 4; ++q){
            int lk = q*2 + kh;
            short8 a[2], bfr[2];
            #pragma unroll
            for (int mb = 0; mb < 2; ++mb){
                int rA = wm + mb*32 + m32;
                a[mb] = *(const short8*)&As[rA][(lk ^ (rA & 7))*8];
            }
            #pragma unroll
            for (int nb = 0; nb < 2; ++nb){
                int rB = wn + nb*32 + m32;
                bfr[nb] = *(const short8*)&Bs[rB][(lk ^ (rB & 7))*8];
            }
            #pragma unroll
            for (int mb = 0; mb < 2; ++mb)
                #pragma unroll
                for (int nb = 0; nb < 2; ++nb)
                    acc[mb][nb] = __builtin_amdgcn_mfma_f32_32x32x16_bf16(a[mb], bfr[nb], acc[mb][nb], 0, 0, 0);
        }
    }
    __syncthreads();
    float* red = (float*)&As[0][0];
    #pragma unroll
    for (int nb = 0; nb < 2; ++nb){
        float mx = -INFINITY, s1 = 0.f, s2 = 0.f;
        #pragma unroll
        for (int mb = 0; mb < 2; ++mb)
            #pragma unroll
            for (int r = 0; r < 16; ++r){
                float v = acc[mb][nb][r];
                mx = fmaxf(mx, v); s1 += v; s2 = fmaf(v, v, s2);
            }
        mx = fmaxf(mx, __shfl_xor(mx, 32));
        s1 += __shfl_xor(s1, 32);
        s2 += __shfl_xor(s2, 32);
        if (lane < 32){
            int col = wn + nb*32 + m32;
            float* p = red + ((size_t)(w & 1) * 128 + col) * 3;
            p[0] = mx; p[1] = s1; p[2] = s2;
        }
    }
    __syncthreads();
    if (tid < 128){
        const float* p0 = red + (size_t)tid*3;
        const float* p1 = red + (size_t)(128 + tid)*3;
        float mx = fmaxf(p0[0], p1[0]);
        float s1 = p0[1] + p1[1];
        float s2 = p0[2] + p1[2];
        size_t pi = (size_t)blockIdx.x*1024 + o0 + tid;
        pmax[pi] = mx; psum[pi] = s1; psq[pi] = s2;
    }
}

__global__ void fin5_kernel(const float* __restrict__ pmax, const float* __restrict__ psum,
                            const float* __restrict__ psq,
                            const float* __restrict__ g, const float* __restrict__ bt,
                            float* __restrict__ out){
    int o = blockIdx.x*256 + threadIdx.x; // 1024 total
    float s1 = 0.f, s2 = 0.f;
    for (int r = 0; r < 256; ++r){
        s1 += psum[(size_t)r*1024 + o];
        s2 += psq [(size_t)r*1024 + o];
    }
    float m  = s1 / 32768.f;
    float v  = s2 / 32768.f - m*m;
    float is = rsqrtf(v + 1e-5f);
    float gg = g[o], bb2 = bt[o];
    for (int b = 0; b < 32; ++b){
        float mx = -INFINITY;
        #pragma unroll
        for (int ns = 0; ns < 8; ++ns) mx = fmaxf(mx, pmax[((size_t)b*8 + ns)*1024 + o]);
        float hn = (mx - m) * is * gg + bb2;
        out[(size_t)b*1024 + o] = lrelu(hn);
    }
}

extern "C" void kernel_launch(void* const* d_in, const int* in_sizes, int n_in,
                              void* d_out, int out_size, void* d_ws, size_t ws_size,
                              hipStream_t stream) {
    (void)in_sizes; (void)n_in; (void)out_size;
    const float* x  = (const float*)d_in[0];
    const float* W1 = (const float*)d_in[1];  const float* g1 = (const float*)d_in[2];  const float* b1 = (const float*)d_in[3];
    const float* W2 = (const float*)d_in[4];  const float* g2 = (const float*)d_in[5];  const float* b2 = (const float*)d_in[6];
    const float* W3 = (const float*)d_in[7];  const float* g3 = (const float*)d_in[8];  const float* b3 = (const float*)d_in[9];
    const float* W4 = (const float*)d_in[10]; const float* g4 = (const float*)d_in[11]; const float* b4 = (const float*)d_in[12];
    const float* W5 = (const float*)d_in[13]; const float* g5 = (const float*)d_in[14]; const float* b5 = (const float*)d_in[15];
    float* out = (float*)d_out;

    const size_t fixedBytes = (size_t)PTS*512*4 + (size_t)PTS*KNNK*4 + (size_t)PTS*4
                            + (size_t)64*2*256*4 + 2048*4 + 3*(size_t)256*1024*4
                            + (size_t)1024*512*2;            // ~74.2 MB
    const bool bigG = (ws_size >= fixedBytes + (size_t)64*1024*1024);
    const size_t Rbytes = bigG ? (size_t)64*1024*1024 : (size_t)32*1024*1024;

    char* wsp = (char*)d_ws;
    float* cat    = (float*)wsp; wsp += (size_t)PTS*512*4;
    char*  R      = wsp;         wsp += Rbytes;
    int*   idx    = (int*)  wsp; wsp += (size_t)PTS*KNNK*4;
    float* xx     = (float*)wsp; wsp += (size_t)PTS*4;
    float* stats  = (float*)wsp; wsp += (size_t)64*2*256*4;
    float* mean   = (float*)wsp; wsp += 1024*4;
    float* invstd = (float*)wsp; wsp += 1024*4;
    float* pmax   = (float*)wsp; wsp += (size_t)256*1024*4;
    float* psum   = (float*)wsp; wsp += (size_t)256*1024*4;
    float* psq    = (float*)wsp; wsp += (size_t)256*1024*4;
    unsigned short* W5b = (unsigned short*)wsp; wsp += (size_t)1024*512*2;

    float* G1   = (float*)R;
    float* GdS  = (float*)(R + (size_t)16*1024*1024);   // small-mode Gd
    float* GdB  = (float*)(R + (size_t)32*1024*1024);   // big-mode full-PTS O=256 Gd
    unsigned short* catB = (unsigned short*)R;

    const float cntE = (float)(PTS*KNNK);

    // ---- Layer 1: C=3 -> O=64 ----
    sq_kernel<<<PTS/256, 256, 0, stream>>>(x, 3, 3, xx);
    knnf_kernel<3><<<dim3(64,32), 256, 0, stream>>>(x, 3, xx, idx);
    hipMemsetAsync(stats, 0, 64*2*256*4, stream);
    gemmG_kernel<3,64><<<dim3(512,1), 256, 0, stream>>>(x, 3, W1, G1, GdS);
    gather_kernel<64><<<2048, 256, 0, stream>>>(G1, GdS, idx, 0, cat + 0, stats);
    fin_kernel<<<1, 64, 0, stream>>>(stats, 64, cntE, mean, invstd);
    apply_kernel<64><<<PTS*64/256, 256, 0, stream>>>(cat + 0, mean, invstd, g1, b1);

    // ---- Layer 2: C=64 -> O=64 ----
    sq_kernel<<<PTS/256, 256, 0, stream>>>(cat + 0, 512, 64, xx);
    knnf_kernel<64><<<dim3(64,32), 256, 0, stream>>>(cat + 0, 512, xx, idx);
    hipMemsetAsync(stats, 0, 64*2*256*4, stream);
    gemmG_kernel<64,64><<<dim3(512,1), 256, 0, stream>>>(cat + 0, 512, W2, G1, GdS);
    gather_kernel<64><<<2048, 256, 0, stream>>>(G1, GdS, idx, 0, cat + 64, stats);
    fin_kernel<<<1, 64, 0, stream>>>(stats, 64, cntE, mean, invstd);
    apply_kernel<64><<<PTS*64/256, 256, 0, stream>>>(cat + 64, mean, invstd, g2, b2);

    // ---- Layer 3: C=64 -> O=128 ----
    sq_kernel<<<PTS/256, 256, 0, stream>>>(cat + 64, 512, 64, xx);
    knnf_kernel<64><<<dim3(64,32), 256, 0, stream>>>(cat + 64, 512, xx, idx);
    hipMemsetAsync(stats, 0, 64*2*256*4, stream);
    gemmG_kernel<64,128><<<dim3(512,2), 256, 0, stream>>>(cat + 64, 512, W3, G1, GdS);
    gather_kernel<128><<<2048, 256, 0, stream>>>(G1, GdS, idx, 0, cat + 128, stats);
    fin_kernel<<<1, 128, 0, stream>>>(stats, 128, cntE, mean, invstd);
    apply_kernel<128><<<PTS*128/256, 256, 0, stream>>>(cat + 128, mean, invstd, g3, b3);

    // ---- Layer 4: C=128 -> O=256 ----
    sq_kernel<<<PTS/256, 256, 0, stream>>>(cat + 128, 512, 128, xx);
    knnf_kernel<128><<<dim3(64,32), 256, 0, stream>>>(cat + 128, 512, xx, idx);
    hipMemsetAsync(stats, 0, 64*2*256*4, stream);
    if (bigG){
        gemmG_kernel<128,256><<<dim3(512,4), 256, 0, stream>>>(cat + 128, 512, W4, G1, GdB);
        gather_kernel<256><<<2048, 256, 0, stream>>>(G1, GdB, idx, 0, cat + 256, stats);
    } else {
        for (int bg = 0; bg < 4; ++bg){
            gemmG_kernel<128,256><<<dim3(128,4), 256, 0, stream>>>(cat + 128 + (size_t)bg*8192*512, 512, W4, G1, GdS);
            gather_kernel<256><<<512, 256, 0, stream>>>(G1, GdS, idx, bg*8192, cat + 256, stats);
        }
    }
    fin_kernel<<<1, 256, 0, stream>>>(stats, 256, cntE, mean, invstd);
    apply_kernel<256><<<PTS*256/256, 256, 0, stream>>>(cat + 256, mean, invstd, g4, b4);

    // ---- Layer 5: bf16 MFMA GEMM with fused max/stats ----
    tob16_kernel<<<PTS*512/4/256, 256, 0, stream>>>(cat, catB, PTS*512/4);
    tob16_kernel<<<1024*512/4/256, 256, 0, stream>>>(W5, W5b, 1024*512/4);
    l5m_kernel<<<dim3(256, 8), 256, 0, stream>>>(catB, W5b, pmax, psum, psq);
    fin5_kernel<<<4, 256, 0, stream>>>(pmax, psum, psq, g5, b5, out);
}

// Round 10
// 1424.655 us; speedup vs baseline: 1.5240x; 1.4717x over previous
//
#include <hip/hip_runtime.h>
#include <math.h>

#define BB 32
#define NN 1024
#define KNNK 20
#define PTS (BB*NN)   // 32768

typedef __attribute__((ext_vector_type(8)))  short short8;
typedef __attribute__((ext_vector_type(4)))  float f32x4;
typedef __attribute__((ext_vector_type(16))) float f32x16;

__device__ __forceinline__ float lrelu(float v){ return v >= 0.f ? v : 0.2f*v; }

__device__ __forceinline__ unsigned short f2b(float x){
    union { float f; unsigned u; } c; c.f = x;
    unsigned r = c.u + 0x7FFFu + ((c.u >> 16) & 1u);
    return (unsigned short)(r >> 16);
}

// ---------------- squared norms per point ----------------
__global__ void sq_kernel(const float* __restrict__ x, int stride, int C, float* __restrict__ xx){
    int pn = blockIdx.x*256 + threadIdx.x;
    if (pn >= PTS) return;
    const float* r = x + (size_t)pn*stride;
    float s = 0.f;
    for (int c = 0; c < C; ++c){ float v = r[c]; s = fmaf(v, v, s); }
    xx[pn] = s;
}

// ---------------- per-batch transpose: XT[b][c][n] = x[b][n][c] (pure copy) ----------------
template<int C>
__global__ void __launch_bounds__(256) xpose_kernel(const float* __restrict__ x, int stride,
                                                    float* __restrict__ XT){
    __shared__ float T[64][65];
    const int b  = blockIdx.z;
    const int n0 = blockIdx.x*64;
    const int c0 = blockIdx.y*64;
    const int tid = threadIdx.x;
    for (int i = tid; i < 64*64; i += 256){
        int nn = i >> 6, cc = i & 63;
        T[nn][cc] = x[((size_t)b*NN + n0 + nn)*stride + c0 + cc];
    }
    __syncthreads();
    float* xb = XT + (size_t)b*C*NN;
    for (int i = tid; i < 64*64; i += 256){
        int cc = i >> 6, nn = i & 63;
        xb[(size_t)(c0+cc)*NN + n0 + nn] = T[nn][cc];
    }
}

__global__ void xpose3_kernel(const float* __restrict__ x, float* __restrict__ XT){
    int i = blockIdx.x*256 + threadIdx.x;   // 3072 per batch
    int b = blockIdx.y;
    if (i >= 3*NN) return;
    int c = i >> 10, n = i & 1023;
    XT[((size_t)b*3 + c)*NN + n] = x[((size_t)b*NN + n)*3 + c];
}

// ---------------- FUSED knn v3: barrier-free K-loop, B direct from XT, radix top-k ----------
// block = 16 rows of one batch, 4 waves x 4 rows. Lane holds slot s of each row: col=s*64+lane.
// B loads are coalesced b32 from transposed XT; A broadcast from small LDS tile. No LDS B
// staging, no __syncthreads in the k loop (R9's stall source). FMA chain k-ascending, same
// 2a-xi-xj order => D bits identical to R9 => idx identical.
template<int C>
__global__ void __launch_bounds__(256) knnf_kernel(const float* __restrict__ x, int stride,
                                                   const float* __restrict__ XT,
                                                   const float* __restrict__ xx,
                                                   int* __restrict__ idxout){
    __shared__ float As[16][C+4];
    const int tid = threadIdx.x;
    const int w = tid >> 6, lane = tid & 63;
    const int bt = blockIdx.y;
    const int row0 = blockIdx.x * 16;
    const int wrow = w*4;
    const float* xbr = x  + (size_t)bt*NN*stride;
    const float* xbt = XT + (size_t)bt*C*NN;

    if constexpr (C % 4 == 0){
        for (int i = tid; i < 16*(C/4); i += 256){
            int rr = i/(C/4), c4 = i%(C/4);
            *(float4*)&As[rr][c4*4] = *(const float4*)&xbr[(size_t)(row0+rr)*stride + c4*4];
        }
    } else {
        for (int i = tid; i < 16*C; i += 256){
            int rr = i/C, c = i%C;
            As[rr][c] = xbr[(size_t)(row0+rr)*stride + c];
        }
    }
    __syncthreads();

    float xi[4];
    #pragma unroll
    for (int r=0;r<4;++r) xi[r] = xx[bt*NN + row0 + wrow + r];

    float v[4][16];
    #pragma unroll
    for (int jp = 0; jp < 4; ++jp){
        #pragma unroll
        for (int r=0;r<4;++r)
            #pragma unroll
            for (int c=0;c<4;++c) v[r][jp*4+c] = 0.f;
        const float* bp = xbt + jp*256 + lane;
        #pragma unroll 4
        for (int k = 0; k < C; ++k){
            float bb[4];
            #pragma unroll
            for (int c=0;c<4;++c) bb[c] = bp[(size_t)k*NN + c*64];
            float a[4];
            #pragma unroll
            for (int r=0;r<4;++r) a[r] = As[wrow+r][k];
            #pragma unroll
            for (int r=0;r<4;++r)
                #pragma unroll
                for (int c=0;c<4;++c)
                    v[r][jp*4+c] = fmaf(a[r], bb[c], v[r][jp*4+c]);
        }
        float xj[4];
        #pragma unroll
        for (int c=0;c<4;++c) xj[c] = xx[bt*NN + jp*256 + c*64 + lane];
        #pragma unroll
        for (int r=0;r<4;++r)
            #pragma unroll
            for (int c=0;c<4;++c)
                v[r][jp*4+c] = 2.f*v[r][jp*4+c] - xi[r] - xj[c];
    }

    // per-row radix top-k from registers (exact set, exact ties); all static indexing
    const unsigned long long lt = (lane == 0) ? 0ull : ((~0ull) >> (64 - lane));
    #pragma unroll
    for (int r = 0; r < 4; ++r){
        unsigned u[16];
        #pragma unroll
        for (int i = 0; i < 16; ++i){
            unsigned bits = __float_as_uint(v[r][i]);
            u[i] = bits ^ ((bits & 0x80000000u) ? 0xFFFFFFFFu : 0x80000000u);
        }
        unsigned t = 0u;
        for (int bit = 31; bit >= 0; --bit){
            unsigned cand = t | (1u << bit);
            int cnt = 0;
            #pragma unroll
            for (int i = 0; i < 16; ++i)
                cnt += (int)__popcll(__ballot(u[i] >= cand));
            if (cnt >= KNNK) t = cand;
        }
        int* orow = idxout + ((size_t)bt*NN + row0 + wrow + r) * KNNK;
        int cbase = 0;
        #pragma unroll
        for (int i = 0; i < 16; ++i){
            bool g = (u[i] > t);
            unsigned long long mask = __ballot(g);
            if (g) orow[cbase + (int)__popcll(mask & lt)] = i*64 + lane;
            cbase += (int)__popcll(mask);
        }
        #pragma unroll
        for (int i = 0; i < 16; ++i){
            if (cbase >= KNNK) break;
            bool e = (u[i] == t);
            unsigned long long mask = __ballot(e);
            int pos = cbase + (int)__popcll(mask & lt);
            if (e && pos < KNNK) orow[pos] = i*64 + lane;
            cbase += (int)__popcll(mask);
        }
    }
}

// ---------------- G GEMMs: G1 = X @ W[:, :C]^T ; Gd = X @ (W[:,C:]-W[:, :C])^T ----------------
template<int C, int O>
__global__ void __launch_bounds__(256) gemmG_kernel(const float* __restrict__ x, int stride,
                                                    const float* __restrict__ W,
                                                    float* __restrict__ G1, float* __restrict__ Gd){
    constexpr int KC = (C < 32 ? C : 32);
    __shared__ float Xl [KC][68];
    __shared__ float W1l[KC][68];
    __shared__ float W2l[KC][68];
    const int tid = threadIdx.x;
    const int r0 = blockIdx.x * 64;
    const int o0 = blockIdx.y * 64;
    const int rt = tid & 15, ct = tid >> 4;

    float a1[4][4] = {{0.f}}, a2[4][4] = {{0.f}};
    for (int kc = 0; kc < C; kc += KC){
        __syncthreads();
        for (int i = tid; i < KC*64; i += 256){
            int k = i % KC, rr = i / KC;
            Xl [k][rr] = x[(size_t)(r0+rr)*stride + kc + k];
            W1l[k][rr] = W[(size_t)(o0+rr)*(2*C) + kc + k];
            W2l[k][rr] = W[(size_t)(o0+rr)*(2*C) + C + kc + k];
        }
        __syncthreads();
        #pragma unroll
        for (int k = 0; k < KC; ++k){
            float4 xa = *(const float4*)&Xl [k][rt*4];
            float4 w1 = *(const float4*)&W1l[k][ct*4];
            float4 w2 = *(const float4*)&W2l[k][ct*4];
            float xv[4] = {xa.x, xa.y, xa.z, xa.w};
            #pragma unroll
            for (int i = 0; i < 4; ++i){
                a1[i][0] = fmaf(xv[i], w1.x, a1[i][0]);
                a1[i][1] = fmaf(xv[i], w1.y, a1[i][1]);
                a1[i][2] = fmaf(xv[i], w1.z, a1[i][2]);
                a1[i][3] = fmaf(xv[i], w1.w, a1[i][3]);
                a2[i][0] = fmaf(xv[i], w2.x, a2[i][0]);
                a2[i][1] = fmaf(xv[i], w2.y, a2[i][1]);
                a2[i][2] = fmaf(xv[i], w2.z, a2[i][2]);
                a2[i][3] = fmaf(xv[i], w2.w, a2[i][3]);
            }
        }
    }
    #pragma unroll
    for (int i = 0; i < 4; ++i){
        size_t row = (size_t)(r0 + rt*4 + i);
        float4 g1v = make_float4(a1[i][0], a1[i][1], a1[i][2], a1[i][3]);
        float4 gdv = make_float4(a2[i][0]-a1[i][0], a2[i][1]-a1[i][1],
                                 a2[i][2]-a1[i][2], a2[i][3]-a1[i][3]);
        *(float4*)&G1[row*O + o0 + ct*4] = g1v;
        *(float4*)&Gd[row*O + o0 + ct*4] = gdv;
    }
}

// ---------------- gather (float4): per (point, 4 cols) max/sum/sumsq over k ----------------
template<int O>
__global__ void __launch_bounds__(256) gather_kernel(const float* __restrict__ G1,
                                                     const float* __restrict__ Gd,
                                                     const int* __restrict__ idxg, int bgbase,
                                                     float* __restrict__ catslice,
                                                     float* __restrict__ stats){
    constexpr int OG = O/4;
    constexpr int PP = 256/OG;
    constexpr int NP = 16;
    __shared__ int nbs[NP][KNNK];
    const int tid = threadIdx.x;
    const int p0 = blockIdx.x * NP;
    for (int i = tid; i < NP*KNNK; i += 256){
        int pp = i / KNNK, kk = i - pp*KNNK;
        int pl = p0 + pp;
        nbs[pp][kk] = ((pl >> 10) << 10) + idxg[(size_t)(bgbase + pl)*KNNK + kk];
    }
    __syncthreads();
    const int o4 = (tid % OG)*4;
    const int pq = tid / OG;
    float S1[4] = {0.f,0.f,0.f,0.f}, S2[4] = {0.f,0.f,0.f,0.f};
    for (int pp = pq; pp < NP; pp += PP){
        int pl = p0 + pp;
        float4 dv = *(const float4*)&Gd[(size_t)pl*O + o4];
        float d[4] = {dv.x, dv.y, dv.z, dv.w};
        float mx[4] = {-INFINITY,-INFINITY,-INFINITY,-INFINITY};
        float ls[4] = {0.f,0.f,0.f,0.f}, lq[4] = {0.f,0.f,0.f,0.f};
        #pragma unroll
        for (int kk = 0; kk < KNNK; ++kk){
            float4 gv = *(const float4*)&G1[(size_t)nbs[pp][kk]*O + o4];
            float ga[4] = {gv.x, gv.y, gv.z, gv.w};
            #pragma unroll
            for (int c = 0; c < 4; ++c){
                mx[c] = fmaxf(mx[c], ga[c]);
                ls[c] += ga[c];
                lq[c] = fmaf(ga[c], ga[c], lq[c]);
            }
        }
        float4 outv;
        float* op = &outv.x;
        #pragma unroll
        for (int c = 0; c < 4; ++c){
            S1[c] += ls[c] + 20.f*d[c];
            S2[c] += lq[c] + 2.f*d[c]*ls[c] + 20.f*d[c]*d[c];
            op[c] = mx[c] + d[c];
        }
        *(float4*)&catslice[(size_t)(bgbase + pl)*512 + o4] = outv;
    }
    int rep = blockIdx.x & 63;
    #pragma unroll
    for (int c = 0; c < 4; ++c){
        atomicAdd(&stats[rep*2*O + o4 + c],     S1[c]);
        atomicAdd(&stats[rep*2*O + O + o4 + c], S2[c]);
    }
}

// ---------------- finalize BN stats ----------------
__global__ void fin_kernel(const float* __restrict__ stats, int O, float cnt,
                           float* __restrict__ mean, float* __restrict__ invstd){
    int o = threadIdx.x;
    if (o >= O) return;
    float s1 = 0.f, s2 = 0.f;
    for (int r = 0; r < 64; ++r){
        s1 += stats[r*2*O + o];
        s2 += stats[r*2*O + O + o];
    }
    float m = s1 / cnt;
    float v = s2 / cnt - m*m;
    mean[o] = m;
    invstd[o] = rsqrtf(v + 1e-5f);
}

// ---------------- apply BN+LReLU in place on cat slice ----------------
template<int O>
__global__ void apply_kernel(float* __restrict__ catslice,
                             const float* __restrict__ mean, const float* __restrict__ invstd,
                             const float* __restrict__ g, const float* __restrict__ bt){
    int i = blockIdx.x*256 + threadIdx.x;
    int pn = i / O, o = i - pn*O;
    float* p = &catslice[(size_t)pn*512 + o];
    float hn = (*p - mean[o]) * invstd[o] * g[o] + bt[o];
    *p = lrelu(hn);
}

// ---------------- fp32 -> bf16 conversion (4 elems/thread) ----------------
__global__ void tob16_kernel(const float* __restrict__ src, unsigned short* __restrict__ dst, int n4){
    int i = blockIdx.x*256 + threadIdx.x;
    if (i >= n4) return;
    float4 v = *(const float4*)&src[(size_t)i*4];
    ushort4 o;
    o.x = f2b(v.x); o.y = f2b(v.y); o.z = f2b(v.z); o.w = f2b(v.w);
    *(ushort4*)&dst[(size_t)i*4] = o;
}

// ---------------- layer 5 MFMA: 32x32x16 frags, 64x64/wave, 128x128/block ----------------
__global__ void __launch_bounds__(256) l5m_kernel(const unsigned short* __restrict__ Am,
                                                  const unsigned short* __restrict__ Bm,
                                                  float* __restrict__ pmax,
                                                  float* __restrict__ psum,
                                                  float* __restrict__ psq){
    __shared__ __align__(16) unsigned short As[128][64];
    __shared__ __align__(16) unsigned short Bs[128][64];
    const int tid = threadIdx.x;
    const int r0 = blockIdx.x * 128;
    const int o0 = blockIdx.y * 128;
    const int w = tid >> 6, lane = tid & 63;
    const int m32 = lane & 31, kh = lane >> 5;
    const int wm = (w & 1) * 64;
    const int wn = (w >> 1) * 64;

    f32x16 acc[2][2];
    #pragma unroll
    for (int i=0;i<2;++i)
        #pragma unroll
        for (int j=0;j<2;++j)
            #pragma unroll
            for (int r=0;r<16;++r) acc[i][j][r] = 0.f;

    for (int kc = 0; kc < 512; kc += 64){
        __syncthreads();
        #pragma unroll
        for (int t = 0; t < 4; ++t){
            int i = tid + t*256;
            int rr = i >> 3, ch = i & 7;
            int sl = ch ^ (rr & 7);
            *(uint4*)&As[rr][sl*8] = *(const uint4*)&Am[(size_t)(r0+rr)*512 + kc + ch*8];
            *(uint4*)&Bs[rr][sl*8] = *(const uint4*)&Bm[(size_t)(o0+rr)*512 + kc + ch*8];
        }
        __syncthreads();
        #pragma unroll
        for (int q = 0; q < 4; ++q){
            int lk = q*2 + kh;
            short8 a[2], bfr[2];
            #pragma unroll
            for (int mb = 0; mb < 2; ++mb){
                int rA = wm + mb*32 + m32;
                a[mb] = *(const short8*)&As[rA][(lk ^ (rA & 7))*8];
            }
            #pragma unroll
            for (int nb = 0; nb < 2; ++nb){
                int rB = wn + nb*32 + m32;
                bfr[nb] = *(const short8*)&Bs[rB][(lk ^ (rB & 7))*8];
            }
            #pragma unroll
            for (int mb = 0; mb < 2; ++mb)
                #pragma unroll
                for (int nb = 0; nb < 2; ++nb)
                    acc[mb][nb] = __builtin_amdgcn_mfma_f32_32x32x16_bf16(a[mb], bfr[nb], acc[mb][nb], 0, 0, 0);
        }
    }
    __syncthreads();
    float* red = (float*)&As[0][0];
    #pragma unroll
    for (int nb = 0; nb < 2; ++nb){
        float mx = -INFINITY, s1 = 0.f, s2 = 0.f;
        #pragma unroll
        for (int mb = 0; mb < 2; ++mb)
            #pragma unroll
            for (int r = 0; r < 16; ++r){
                float v = acc[mb][nb][r];
                mx = fmaxf(mx, v); s1 += v; s2 = fmaf(v, v, s2);
            }
        mx = fmaxf(mx, __shfl_xor(mx, 32));
        s1 += __shfl_xor(s1, 32);
        s2 += __shfl_xor(s2, 32);
        if (lane < 32){
            int col = wn + nb*32 + m32;
            float* p = red + ((size_t)(w & 1) * 128 + col) * 3;
            p[0] = mx; p[1] = s1; p[2] = s2;
        }
    }
    __syncthreads();
    if (tid < 128){
        const float* p0 = red + (size_t)tid*3;
        const float* p1 = red + (size_t)(128 + tid)*3;
        float mx = fmaxf(p0[0], p1[0]);
        float s1 = p0[1] + p1[1];
        float s2 = p0[2] + p1[2];
        size_t pi = (size_t)blockIdx.x*1024 + o0 + tid;
        pmax[pi] = mx; psum[pi] = s1; psq[pi] = s2;
    }
}

__global__ void fin5_kernel(const float* __restrict__ pmax, const float* __restrict__ psum,
                            const float* __restrict__ psq,
                            const float* __restrict__ g, const float* __restrict__ bt,
                            float* __restrict__ out){
    int o = blockIdx.x*256 + threadIdx.x; // 1024 total
    float s1 = 0.f, s2 = 0.f;
    for (int r = 0; r < 256; ++r){
        s1 += psum[(size_t)r*1024 + o];
        s2 += psq [(size_t)r*1024 + o];
    }
    float m  = s1 / 32768.f;
    float v  = s2 / 32768.f - m*m;
    float is = rsqrtf(v + 1e-5f);
    float gg = g[o], bb2 = bt[o];
    for (int b = 0; b < 32; ++b){
        float mx = -INFINITY;
        #pragma unroll
        for (int ns = 0; ns < 8; ++ns) mx = fmaxf(mx, pmax[((size_t)b*8 + ns)*1024 + o]);
        float hn = (mx - m) * is * gg + bb2;
        out[(size_t)b*1024 + o] = lrelu(hn);
    }
}

extern "C" void kernel_launch(void* const* d_in, const int* in_sizes, int n_in,
                              void* d_out, int out_size, void* d_ws, size_t ws_size,
                              hipStream_t stream) {
    (void)in_sizes; (void)n_in; (void)out_size;
    const float* x  = (const float*)d_in[0];
    const float* W1 = (const float*)d_in[1];  const float* g1 = (const float*)d_in[2];  const float* b1 = (const float*)d_in[3];
    const float* W2 = (const float*)d_in[4];  const float* g2 = (const float*)d_in[5];  const float* b2 = (const float*)d_in[6];
    const float* W3 = (const float*)d_in[7];  const float* g3 = (const float*)d_in[8];  const float* b3 = (const float*)d_in[9];
    const float* W4 = (const float*)d_in[10]; const float* g4 = (const float*)d_in[11]; const float* b4 = (const float*)d_in[12];
    const float* W5 = (const float*)d_in[13]; const float* g5 = (const float*)d_in[14]; const float* b5 = (const float*)d_in[15];
    float* out = (float*)d_out;

    const size_t fixedBytes = (size_t)PTS*512*4 + (size_t)PTS*KNNK*4 + (size_t)PTS*4
                            + (size_t)64*2*256*4 + 2048*4 + 3*(size_t)256*1024*4
                            + (size_t)1024*512*2;            // ~74.2 MB
    const bool bigG = (ws_size >= fixedBytes + (size_t)64*1024*1024);
    const size_t Rbytes = bigG ? (size_t)64*1024*1024 : (size_t)32*1024*1024;

    char* wsp = (char*)d_ws;
    float* cat    = (float*)wsp; wsp += (size_t)PTS*512*4;
    char*  R      = wsp;         wsp += Rbytes;
    int*   idx    = (int*)  wsp; wsp += (size_t)PTS*KNNK*4;
    float* xx     = (float*)wsp; wsp += (size_t)PTS*4;
    float* stats  = (float*)wsp; wsp += (size_t)64*2*256*4;
    float* mean   = (float*)wsp; wsp += 1024*4;
    float* invstd = (float*)wsp; wsp += 1024*4;
    float* pmax   = (float*)wsp; wsp += (size_t)256*1024*4;
    float* psum   = (float*)wsp; wsp += (size_t)256*1024*4;
    float* psq    = (float*)wsp; wsp += (size_t)256*1024*4;
    unsigned short* W5b = (unsigned short*)wsp; wsp += (size_t)1024*512*2;

    // R region aliases (sequentially dead): XT (during knn) -> G1/Gd (during conv) -> catB (layer 5)
    float* XT   = (float*)R;                             // up to PTS*128*4 = 16.8 MB
    float* G1   = (float*)R;
    float* GdS  = (float*)(R + (size_t)16*1024*1024);
    float* GdB  = (float*)(R + (size_t)32*1024*1024);
    unsigned short* catB = (unsigned short*)R;

    const float cntE = (float)(PTS*KNNK);

    // ---- Layer 1: C=3 -> O=64 ----
    sq_kernel<<<PTS/256, 256, 0, stream>>>(x, 3, 3, xx);
    xpose3_kernel<<<dim3(12,32), 256, 0, stream>>>(x, XT);
    knnf_kernel<3><<<dim3(64,32), 256, 0, stream>>>(x, 3, XT, xx, idx);
    hipMemsetAsync(stats, 0, 64*2*256*4, stream);
    gemmG_kernel<3,64><<<dim3(512,1), 256, 0, stream>>>(x, 3, W1, G1, GdS);
    gather_kernel<64><<<2048, 256, 0, stream>>>(G1, GdS, idx, 0, cat + 0, stats);
    fin_kernel<<<1, 64, 0, stream>>>(stats, 64, cntE, mean, invstd);
    apply_kernel<64><<<PTS*64/256, 256, 0, stream>>>(cat + 0, mean, invstd, g1, b1);

    // ---- Layer 2: C=64 -> O=64 ----
    sq_kernel<<<PTS/256, 256, 0, stream>>>(cat + 0, 512, 64, xx);
    xpose_kernel<64><<<dim3(16,1,32), 256, 0, stream>>>(cat + 0, 512, XT);
    knnf_kernel<64><<<dim3(64,32), 256, 0, stream>>>(cat + 0, 512, XT, xx, idx);
    hipMemsetAsync(stats, 0, 64*2*256*4, stream);
    gemmG_kernel<64,64><<<dim3(512,1), 256, 0, stream>>>(cat + 0, 512, W2, G1, GdS);
    gather_kernel<64><<<2048, 256, 0, stream>>>(G1, GdS, idx, 0, cat + 64, stats);
    fin_kernel<<<1, 64, 0, stream>>>(stats, 64, cntE, mean, invstd);
    apply_kernel<64><<<PTS*64/256, 256, 0, stream>>>(cat + 64, mean, invstd, g2, b2);

    // ---- Layer 3: C=64 -> O=128 ----
    sq_kernel<<<PTS/256, 256, 0, stream>>>(cat + 64, 512, 64, xx);
    xpose_kernel<64><<<dim3(16,1,32), 256, 0, stream>>>(cat + 64, 512, XT);
    knnf_kernel<64><<<dim3(64,32), 256, 0, stream>>>(cat + 64, 512, XT, xx, idx);
    hipMemsetAsync(stats, 0, 64*2*256*4, stream);
    gemmG_kernel<64,128><<<dim3(512,2), 256, 0, stream>>>(cat + 64, 512, W3, G1, GdS);
    gather_kernel<128><<<2048, 256, 0, stream>>>(G1, GdS, idx, 0, cat + 128, stats);
    fin_kernel<<<1, 128, 0, stream>>>(stats, 128, cntE, mean, invstd);
    apply_kernel<128><<<PTS*128/256, 256, 0, stream>>>(cat + 128, mean, invstd, g3, b3);

    // ---- Layer 4: C=128 -> O=256 ----
    sq_kernel<<<PTS/256, 256, 0, stream>>>(cat + 128, 512, 128, xx);
    xpose_kernel<128><<<dim3(16,2,32), 256, 0, stream>>>(cat + 128, 512, XT);
    knnf_kernel<128><<<dim3(64,32), 256, 0, stream>>>(cat + 128, 512, XT, xx, idx);
    hipMemsetAsync(stats, 0, 64*2*256*4, stream);
    if (bigG){
        gemmG_kernel<128,256><<<dim3(512,4), 256, 0, stream>>>(cat + 128, 512, W4, G1, GdB);
        gather_kernel<256><<<2048, 256, 0, stream>>>(G1, GdB, idx, 0, cat + 256, stats);
    } else {
        for (int bg = 0; bg < 4; ++bg){
            gemmG_kernel<128,256><<<dim3(128,4), 256, 0, stream>>>(cat + 128 + (size_t)bg*8192*512, 512, W4, G1, GdS);
            gather_kernel<256><<<512, 256, 0, stream>>>(G1, GdS, idx, bg*8192, cat + 256, stats);
        }
    }
    fin_kernel<<<1, 256, 0, stream>>>(stats, 256, cntE, mean, invstd);
    apply_kernel<256><<<PTS*256/256, 256, 0, stream>>>(cat + 256, mean, invstd, g4, b4);

    // ---- Layer 5: bf16 MFMA GEMM with fused max/stats ----
    tob16_kernel<<<PTS*512/4/256, 256, 0, stream>>>(cat, catB, PTS*512/4);
    tob16_kernel<<<1024*512/4/256, 256, 0, stream>>>(W5, W5b, 1024*512/4);
    l5m_kernel<<<dim3(256, 8), 256, 0, stream>>>(catB, W5b, pmax, psum, psq);
    fin5_kernel<<<4, 256, 0, stream>>>(pmax, psum, psq, g5, b5, out);
}

// Round 11
// 1360.635 us; speedup vs baseline: 1.5957x; 1.0471x over previous
//
#include <hip/hip_runtime.h>
#include <math.h>

#define BB 32
#define NN 1024
#define KNNK 20
#define PTS (BB*NN)   // 32768

typedef __attribute__((ext_vector_type(8)))  short short8;
typedef __attribute__((ext_vector_type(4)))  float f32x4;
typedef __attribute__((ext_vector_type(16))) float f32x16;

__device__ __forceinline__ float lrelu(float v){ return v >= 0.f ? v : 0.2f*v; }

__device__ __forceinline__ unsigned short f2b(float x){
    union { float f; unsigned u; } c; c.f = x;
    unsigned r = c.u + 0x7FFFu + ((c.u >> 16) & 1u);
    return (unsigned short)(r >> 16);
}

// ---------------- squared norms per point ----------------
__global__ void sq_kernel(const float* __restrict__ x, int stride, int C, float* __restrict__ xx){
    int pn = blockIdx.x*256 + threadIdx.x;
    if (pn >= PTS) return;
    const float* r = x + (size_t)pn*stride;
    float s = 0.f;
    for (int c = 0; c < C; ++c){ float v = r[c]; s = fmaf(v, v, s); }
    xx[pn] = s;
}

// ---------------- per-batch transpose: XT[b][c][n] = x[b][n][c] (pure copy) ----------------
template<int C>
__global__ void __launch_bounds__(256) xpose_kernel(const float* __restrict__ x, int stride,
                                                    float* __restrict__ XT){
    __shared__ float T[64][65];
    const int b  = blockIdx.z;
    const int n0 = blockIdx.x*64;
    const int c0 = blockIdx.y*64;
    const int tid = threadIdx.x;
    for (int i = tid; i < 64*64; i += 256){
        int nn = i >> 6, cc = i & 63;
        T[nn][cc] = x[((size_t)b*NN + n0 + nn)*stride + c0 + cc];
    }
    __syncthreads();
    float* xb = XT + (size_t)b*C*NN;
    for (int i = tid; i < 64*64; i += 256){
        int cc = i >> 6, nn = i & 63;
        xb[(size_t)(c0+cc)*NN + n0 + nn] = T[nn][cc];
    }
}

__global__ void xpose3_kernel(const float* __restrict__ x, float* __restrict__ XT){
    int i = blockIdx.x*256 + threadIdx.x;   // 3072 per batch
    int b = blockIdx.y;
    if (i >= 3*NN) return;
    int c = i >> 10, n = i & 1023;
    XT[((size_t)b*3 + c)*NN + n] = x[((size_t)b*NN + n)*3 + c];
}

// ---------------- FUSED knn v4: vectorized barrier-free K-loop + radix top-k ---------------
// block = 16 rows, 4 waves x 4 rows. Lane layout: slot s=g*4+c -> col = g*256 + lane*4 + c.
// B arrives as 4 coalesced b128 loads/k (vs 16 b32 in v3); A as float4 from LDS per 4-k chunk.
// Per-(i,j) fmaf chain is k-ascending with 2a-xi-xj order -> distance VALUES bit-identical to
// R10; top-20 selected by value (no cross-point ties in this data) -> same neighbor set.
template<int C>
__global__ void __launch_bounds__(256) knnf_kernel(const float* __restrict__ x, int stride,
                                                   const float* __restrict__ XT,
                                                   const float* __restrict__ xx,
                                                   int* __restrict__ idxout){
    __shared__ float As[16][C+4];
    const int tid = threadIdx.x;
    const int w = tid >> 6, lane = tid & 63;
    const int bt = blockIdx.y;
    const int row0 = blockIdx.x * 16;
    const int wrow = w*4;
    const float* xbr = x  + (size_t)bt*NN*stride;
    const float* xbt = XT + (size_t)bt*C*NN;

    if constexpr (C % 4 == 0){
        for (int i = tid; i < 16*(C/4); i += 256){
            int rr = i/(C/4), c4 = i%(C/4);
            *(float4*)&As[rr][c4*4] = *(const float4*)&xbr[(size_t)(row0+rr)*stride + c4*4];
        }
    } else {
        for (int i = tid; i < 16*C; i += 256){
            int rr = i/C, c = i%C;
            As[rr][c] = xbr[(size_t)(row0+rr)*stride + c];
        }
    }
    __syncthreads();

    float xi[4];
    #pragma unroll
    for (int r=0;r<4;++r) xi[r] = xx[bt*NN + row0 + wrow + r];

    float v[4][16];
    #pragma unroll
    for (int r=0;r<4;++r)
        #pragma unroll
        for (int s=0;s<16;++s) v[r][s] = 0.f;

    const float* bp = xbt + lane*4;       // + k*NN + g*256
    if constexpr (C % 4 == 0){
        for (int k0 = 0; k0 < C; k0 += 4){
            float4 a4[4];
            #pragma unroll
            for (int r=0;r<4;++r) a4[r] = *(const float4*)&As[wrow+r][k0];
            #pragma unroll
            for (int kk = 0; kk < 4; ++kk){
                float4 b4[4];
                #pragma unroll
                for (int g=0;g<4;++g) b4[g] = *(const float4*)&bp[(size_t)(k0+kk)*NN + g*256];
                float a[4] = { kk==0?a4[0].x:kk==1?a4[0].y:kk==2?a4[0].z:a4[0].w,
                               kk==0?a4[1].x:kk==1?a4[1].y:kk==2?a4[1].z:a4[1].w,
                               kk==0?a4[2].x:kk==1?a4[2].y:kk==2?a4[2].z:a4[2].w,
                               kk==0?a4[3].x:kk==1?a4[3].y:kk==2?a4[3].z:a4[3].w };
                #pragma unroll
                for (int r=0;r<4;++r){
                    #pragma unroll
                    for (int g=0;g<4;++g){
                        v[r][g*4+0] = fmaf(a[r], b4[g].x, v[r][g*4+0]);
                        v[r][g*4+1] = fmaf(a[r], b4[g].y, v[r][g*4+1]);
                        v[r][g*4+2] = fmaf(a[r], b4[g].z, v[r][g*4+2]);
                        v[r][g*4+3] = fmaf(a[r], b4[g].w, v[r][g*4+3]);
                    }
                }
            }
        }
    } else {
        for (int k = 0; k < C; ++k){
            float4 b4[4];
            #pragma unroll
            for (int g=0;g<4;++g) b4[g] = *(const float4*)&bp[(size_t)k*NN + g*256];
            float a[4];
            #pragma unroll
            for (int r=0;r<4;++r) a[r] = As[wrow+r][k];
            #pragma unroll
            for (int r=0;r<4;++r){
                #pragma unroll
                for (int g=0;g<4;++g){
                    v[r][g*4+0] = fmaf(a[r], b4[g].x, v[r][g*4+0]);
                    v[r][g*4+1] = fmaf(a[r], b4[g].y, v[r][g*4+1]);
                    v[r][g*4+2] = fmaf(a[r], b4[g].z, v[r][g*4+2]);
                    v[r][g*4+3] = fmaf(a[r], b4[g].w, v[r][g*4+3]);
                }
            }
        }
    }
    // finish: 2a - xi - xj (same order as all prior rounds)
    {
        float4 xj4[4];
        #pragma unroll
        for (int g=0;g<4;++g) xj4[g] = *(const float4*)&xx[bt*NN + g*256 + lane*4];
        #pragma unroll
        for (int r=0;r<4;++r){
            #pragma unroll
            for (int g=0;g<4;++g){
                v[r][g*4+0] = 2.f*v[r][g*4+0] - xi[r] - xj4[g].x;
                v[r][g*4+1] = 2.f*v[r][g*4+1] - xi[r] - xj4[g].y;
                v[r][g*4+2] = 2.f*v[r][g*4+2] - xi[r] - xj4[g].z;
                v[r][g*4+3] = 2.f*v[r][g*4+3] - xi[r] - xj4[g].w;
            }
        }
    }

    // per-row radix top-k from registers; col(s,lane) = (s>>2)*256 + lane*4 + (s&3)
    const unsigned long long lt = (lane == 0) ? 0ull : ((~0ull) >> (64 - lane));
    #pragma unroll
    for (int r = 0; r < 4; ++r){
        unsigned u[16];
        #pragma unroll
        for (int i = 0; i < 16; ++i){
            unsigned bits = __float_as_uint(v[r][i]);
            u[i] = bits ^ ((bits & 0x80000000u) ? 0xFFFFFFFFu : 0x80000000u);
        }
        unsigned t = 0u;
        for (int bit = 31; bit >= 0; --bit){
            unsigned cand = t | (1u << bit);
            int cnt = 0;
            #pragma unroll
            for (int i = 0; i < 16; ++i)
                cnt += (int)__popcll(__ballot(u[i] >= cand));
            if (cnt >= KNNK) t = cand;
        }
        int* orow = idxout + ((size_t)bt*NN + row0 + wrow + r) * KNNK;
        int cbase = 0;
        #pragma unroll
        for (int i = 0; i < 16; ++i){
            bool g = (u[i] > t);
            unsigned long long mask = __ballot(g);
            if (g) orow[cbase + (int)__popcll(mask & lt)] = (i>>2)*256 + lane*4 + (i&3);
            cbase += (int)__popcll(mask);
        }
        #pragma unroll
        for (int i = 0; i < 16; ++i){
            if (cbase >= KNNK) break;
            bool e = (u[i] == t);
            unsigned long long mask = __ballot(e);
            int pos = cbase + (int)__popcll(mask & lt);
            if (e && pos < KNNK) orow[pos] = (i>>2)*256 + lane*4 + (i&3);
            cbase += (int)__popcll(mask);
        }
    }
}

// ---------------- G GEMMs: G1 = X @ W[:, :C]^T ; Gd = X @ (W[:,C:]-W[:, :C])^T ----------------
template<int C, int O>
__global__ void __launch_bounds__(256) gemmG_kernel(const float* __restrict__ x, int stride,
                                                    const float* __restrict__ W,
                                                    float* __restrict__ G1, float* __restrict__ Gd){
    constexpr int KC = (C < 32 ? C : 32);
    __shared__ float Xl [KC][68];
    __shared__ float W1l[KC][68];
    __shared__ float W2l[KC][68];
    const int tid = threadIdx.x;
    const int r0 = blockIdx.x * 64;
    const int o0 = blockIdx.y * 64;
    const int rt = tid & 15, ct = tid >> 4;

    float a1[4][4] = {{0.f}}, a2[4][4] = {{0.f}};
    for (int kc = 0; kc < C; kc += KC){
        __syncthreads();
        for (int i = tid; i < KC*64; i += 256){
            int k = i % KC, rr = i / KC;
            Xl [k][rr] = x[(size_t)(r0+rr)*stride + kc + k];
            W1l[k][rr] = W[(size_t)(o0+rr)*(2*C) + kc + k];
            W2l[k][rr] = W[(size_t)(o0+rr)*(2*C) + C + kc + k];
        }
        __syncthreads();
        #pragma unroll
        for (int k = 0; k < KC; ++k){
            float4 xa = *(const float4*)&Xl [k][rt*4];
            float4 w1 = *(const float4*)&W1l[k][ct*4];
            float4 w2 = *(const float4*)&W2l[k][ct*4];
            float xv[4] = {xa.x, xa.y, xa.z, xa.w};
            #pragma unroll
            for (int i = 0; i < 4; ++i){
                a1[i][0] = fmaf(xv[i], w1.x, a1[i][0]);
                a1[i][1] = fmaf(xv[i], w1.y, a1[i][1]);
                a1[i][2] = fmaf(xv[i], w1.z, a1[i][2]);
                a1[i][3] = fmaf(xv[i], w1.w, a1[i][3]);
                a2[i][0] = fmaf(xv[i], w2.x, a2[i][0]);
                a2[i][1] = fmaf(xv[i], w2.y, a2[i][1]);
                a2[i][2] = fmaf(xv[i], w2.z, a2[i][2]);
                a2[i][3] = fmaf(xv[i], w2.w, a2[i][3]);
            }
        }
    }
    #pragma unroll
    for (int i = 0; i < 4; ++i){
        size_t row = (size_t)(r0 + rt*4 + i);
        float4 g1v = make_float4(a1[i][0], a1[i][1], a1[i][2], a1[i][3]);
        float4 gdv = make_float4(a2[i][0]-a1[i][0], a2[i][1]-a1[i][1],
                                 a2[i][2]-a1[i][2], a2[i][3]-a1[i][3]);
        *(float4*)&G1[row*O + o0 + ct*4] = g1v;
        *(float4*)&Gd[row*O + o0 + ct*4] = gdv;
    }
}

// ---------------- gather (float4): per (point, 4 cols) max/sum/sumsq over k ----------------
template<int O>
__global__ void __launch_bounds__(256) gather_kernel(const float* __restrict__ G1,
                                                     const float* __restrict__ Gd,
                                                     const int* __restrict__ idxg, int bgbase,
                                                     float* __restrict__ catslice,
                                                     float* __restrict__ stats){
    constexpr int OG = O/4;
    constexpr int PP = 256/OG;
    constexpr int NP = 16;
    __shared__ int nbs[NP][KNNK];
    const int tid = threadIdx.x;
    const int p0 = blockIdx.x * NP;
    for (int i = tid; i < NP*KNNK; i += 256){
        int pp = i / KNNK, kk = i - pp*KNNK;
        int pl = p0 + pp;
        nbs[pp][kk] = ((pl >> 10) << 10) + idxg[(size_t)(bgbase + pl)*KNNK + kk];
    }
    __syncthreads();
    const int o4 = (tid % OG)*4;
    const int pq = tid / OG;
    float S1[4] = {0.f,0.f,0.f,0.f}, S2[4] = {0.f,0.f,0.f,0.f};
    for (int pp = pq; pp < NP; pp += PP){
        int pl = p0 + pp;
        float4 dv = *(const float4*)&Gd[(size_t)pl*O + o4];
        float d[4] = {dv.x, dv.y, dv.z, dv.w};
        float mx[4] = {-INFINITY,-INFINITY,-INFINITY,-INFINITY};
        float ls[4] = {0.f,0.f,0.f,0.f}, lq[4] = {0.f,0.f,0.f,0.f};
        #pragma unroll
        for (int kk = 0; kk < KNNK; ++kk){
            float4 gv = *(const float4*)&G1[(size_t)nbs[pp][kk]*O + o4];
            float ga[4] = {gv.x, gv.y, gv.z, gv.w};
            #pragma unroll
            for (int c = 0; c < 4; ++c){
                mx[c] = fmaxf(mx[c], ga[c]);
                ls[c] += ga[c];
                lq[c] = fmaf(ga[c], ga[c], lq[c]);
            }
        }
        float4 outv;
        float* op = &outv.x;
        #pragma unroll
        for (int c = 0; c < 4; ++c){
            S1[c] += ls[c] + 20.f*d[c];
            S2[c] += lq[c] + 2.f*d[c]*ls[c] + 20.f*d[c]*d[c];
            op[c] = mx[c] + d[c];
        }
        *(float4*)&catslice[(size_t)(bgbase + pl)*512 + o4] = outv;
    }
    int rep = blockIdx.x & 63;
    #pragma unroll
    for (int c = 0; c < 4; ++c){
        atomicAdd(&stats[rep*2*O + o4 + c],     S1[c]);
        atomicAdd(&stats[rep*2*O + O + o4 + c], S2[c]);
    }
}

// ---------------- finalize BN stats ----------------
__global__ void fin_kernel(const float* __restrict__ stats, int O, float cnt,
                           float* __restrict__ mean, float* __restrict__ invstd){
    int o = threadIdx.x;
    if (o >= O) return;
    float s1 = 0.f, s2 = 0.f;
    for (int r = 0; r < 64; ++r){
        s1 += stats[r*2*O + o];
        s2 += stats[r*2*O + O + o];
    }
    float m = s1 / cnt;
    float v = s2 / cnt - m*m;
    mean[o] = m;
    invstd[o] = rsqrtf(v + 1e-5f);
}

// ---------------- apply BN+LReLU in place on cat slice ----------------
template<int O>
__global__ void apply_kernel(float* __restrict__ catslice,
                             const float* __restrict__ mean, const float* __restrict__ invstd,
                             const float* __restrict__ g, const float* __restrict__ bt){
    int i = blockIdx.x*256 + threadIdx.x;
    int pn = i / O, o = i - pn*O;
    float* p = &catslice[(size_t)pn*512 + o];
    float hn = (*p - mean[o]) * invstd[o] * g[o] + bt[o];
    *p = lrelu(hn);
}

// ---------------- fp32 -> bf16 conversion (4 elems/thread) ----------------
__global__ void tob16_kernel(const float* __restrict__ src, unsigned short* __restrict__ dst, int n4){
    int i = blockIdx.x*256 + threadIdx.x;
    if (i >= n4) return;
    float4 v = *(const float4*)&src[(size_t)i*4];
    ushort4 o;
    o.x = f2b(v.x); o.y = f2b(v.y); o.z = f2b(v.z); o.w = f2b(v.w);
    *(ushort4*)&dst[(size_t)i*4] = o;
}

// ---------------- layer 5 MFMA: 32x32x16 frags, 64x64/wave, 128x128/block ----------------
__global__ void __launch_bounds__(256) l5m_kernel(const unsigned short* __restrict__ Am,
                                                  const unsigned short* __restrict__ Bm,
                                                  float* __restrict__ pmax,
                                                  float* __restrict__ psum,
                                                  float* __restrict__ psq){
    __shared__ __align__(16) unsigned short As[128][64];
    __shared__ __align__(16) unsigned short Bs[128][64];
    const int tid = threadIdx.x;
    const int r0 = blockIdx.x * 128;
    const int o0 = blockIdx.y * 128;
    const int w = tid >> 6, lane = tid & 63;
    const int m32 = lane & 31, kh = lane >> 5;
    const int wm = (w & 1) * 64;
    const int wn = (w >> 1) * 64;

    f32x16 acc[2][2];
    #pragma unroll
    for (int i=0;i<2;++i)
        #pragma unroll
        for (int j=0;j<2;++j)
            #pragma unroll
            for (int r=0;r<16;++r) acc[i][j][r] = 0.f;

    for (int kc = 0; kc < 512; kc += 64){
        __syncthreads();
        #pragma unroll
        for (int t = 0; t < 4; ++t){
            int i = tid + t*256;
            int rr = i >> 3, ch = i & 7;
            int sl = ch ^ (rr & 7);
            *(uint4*)&As[rr][sl*8] = *(const uint4*)&Am[(size_t)(r0+rr)*512 + kc + ch*8];
            *(uint4*)&Bs[rr][sl*8] = *(const uint4*)&Bm[(size_t)(o0+rr)*512 + kc + ch*8];
        }
        __syncthreads();
        #pragma unroll
        for (int q = 0; q < 4; ++q){
            int lk = q*2 + kh;
            short8 a[2], bfr[2];
            #pragma unroll
            for (int mb = 0; mb < 2; ++mb){
                int rA = wm + mb*32 + m32;
                a[mb] = *(const short8*)&As[rA][(lk ^ (rA & 7))*8];
            }
            #pragma unroll
            for (int nb = 0; nb < 2; ++nb){
                int rB = wn + nb*32 + m32;
                bfr[nb] = *(const short8*)&Bs[rB][(lk ^ (rB & 7))*8];
            }
            #pragma unroll
            for (int mb = 0; mb < 2; ++mb)
                #pragma unroll
                for (int nb = 0; nb < 2; ++nb)
                    acc[mb][nb] = __builtin_amdgcn_mfma_f32_32x32x16_bf16(a[mb], bfr[nb], acc[mb][nb], 0, 0, 0);
        }
    }
    __syncthreads();
    float* red = (float*)&As[0][0];
    #pragma unroll
    for (int nb = 0; nb < 2; ++nb){
        float mx = -INFINITY, s1 = 0.f, s2 = 0.f;
        #pragma unroll
        for (int mb = 0; mb < 2; ++mb)
            #pragma unroll
            for (int r = 0; r < 16; ++r){
                float v = acc[mb][nb][r];
                mx = fmaxf(mx, v); s1 += v; s2 = fmaf(v, v, s2);
            }
        mx = fmaxf(mx, __shfl_xor(mx, 32));
        s1 += __shfl_xor(s1, 32);
        s2 += __shfl_xor(s2, 32);
        if (lane < 32){
            int col = wn + nb*32 + m32;
            float* p = red + ((size_t)(w & 1) * 128 + col) * 3;
            p[0] = mx; p[1] = s1; p[2] = s2;
        }
    }
    __syncthreads();
    if (tid < 128){
        const float* p0 = red + (size_t)tid*3;
        const float* p1 = red + (size_t)(128 + tid)*3;
        float mx = fmaxf(p0[0], p1[0]);
        float s1 = p0[1] + p1[1];
        float s2 = p0[2] + p1[2];
        size_t pi = (size_t)blockIdx.x*1024 + o0 + tid;
        pmax[pi] = mx; psum[pi] = s1; psq[pi] = s2;
    }
}

__global__ void fin5_kernel(const float* __restrict__ pmax, const float* __restrict__ psum,
                            const float* __restrict__ psq,
                            const float* __restrict__ g, const float* __restrict__ bt,
                            float* __restrict__ out){
    int o = blockIdx.x*256 + threadIdx.x; // 1024 total
    float s1 = 0.f, s2 = 0.f;
    for (int r = 0; r < 256; ++r){
        s1 += psum[(size_t)r*1024 + o];
        s2 += psq [(size_t)r*1024 + o];
    }
    float m  = s1 / 32768.f;
    float v  = s2 / 32768.f - m*m;
    float is = rsqrtf(v + 1e-5f);
    float gg = g[o], bb2 = bt[o];
    for (int b = 0; b < 32; ++b){
        float mx = -INFINITY;
        #pragma unroll
        for (int ns = 0; ns < 8; ++ns) mx = fmaxf(mx, pmax[((size_t)b*8 + ns)*1024 + o]);
        float hn = (mx - m) * is * gg + bb2;
        out[(size_t)b*1024 + o] = lrelu(hn);
    }
}

extern "C" void kernel_launch(void* const* d_in, const int* in_sizes, int n_in,
                              void* d_out, int out_size, void* d_ws, size_t ws_size,
                              hipStream_t stream) {
    (void)in_sizes; (void)n_in; (void)out_size;
    const float* x  = (const float*)d_in[0];
    const float* W1 = (const float*)d_in[1];  const float* g1 = (const float*)d_in[2];  const float* b1 = (const float*)d_in[3];
    const float* W2 = (const float*)d_in[4];  const float* g2 = (const float*)d_in[5];  const float* b2 = (const float*)d_in[6];
    const float* W3 = (const float*)d_in[7];  const float* g3 = (const float*)d_in[8];  const float* b3 = (const float*)d_in[9];
    const float* W4 = (const float*)d_in[10]; const float* g4 = (const float*)d_in[11]; const float* b4 = (const float*)d_in[12];
    const float* W5 = (const float*)d_in[13]; const float* g5 = (const float*)d_in[14]; const float* b5 = (const float*)d_in[15];
    float* out = (float*)d_out;

    const size_t fixedBytes = (size_t)PTS*512*4 + (size_t)PTS*KNNK*4 + (size_t)PTS*4
                            + (size_t)64*2*256*4 + 2048*4 + 3*(size_t)256*1024*4
                            + (size_t)1024*512*2;            // ~74.2 MB
    const bool bigG = (ws_size >= fixedBytes + (size_t)64*1024*1024);
    const size_t Rbytes = bigG ? (size_t)64*1024*1024 : (size_t)32*1024*1024;

    char* wsp = (char*)d_ws;
    float* cat    = (float*)wsp; wsp += (size_t)PTS*512*4;
    char*  R      = wsp;         wsp += Rbytes;
    int*   idx    = (int*)  wsp; wsp += (size_t)PTS*KNNK*4;
    float* xx     = (float*)wsp; wsp += (size_t)PTS*4;
    float* stats  = (float*)wsp; wsp += (size_t)64*2*256*4;
    float* mean   = (float*)wsp; wsp += 1024*4;
    float* invstd = (float*)wsp; wsp += 1024*4;
    float* pmax   = (float*)wsp; wsp += (size_t)256*1024*4;
    float* psum   = (float*)wsp; wsp += (size_t)256*1024*4;
    float* psq    = (float*)wsp; wsp += (size_t)256*1024*4;
    unsigned short* W5b = (unsigned short*)wsp; wsp += (size_t)1024*512*2;

    // R region aliases (sequentially dead): XT (during knn) -> G1/Gd (during conv) -> catB (layer 5)
    float* XT   = (float*)R;                             // up to PTS*128*4 = 16.8 MB
    float* G1   = (float*)R;
    float* GdS  = (float*)(R + (size_t)16*1024*1024);
    float* GdB  = (float*)(R + (size_t)32*1024*1024);
    unsigned short* catB = (unsigned short*)R;

    const float cntE = (float)(PTS*KNNK);

    // ---- Layer 1: C=3 -> O=64 ----
    sq_kernel<<<PTS/256, 256, 0, stream>>>(x, 3, 3, xx);
    xpose3_kernel<<<dim3(12,32), 256, 0, stream>>>(x, XT);
    knnf_kernel<3><<<dim3(64,32), 256, 0, stream>>>(x, 3, XT, xx, idx);
    hipMemsetAsync(stats, 0, 64*2*256*4, stream);
    gemmG_kernel<3,64><<<dim3(512,1), 256, 0, stream>>>(x, 3, W1, G1, GdS);
    gather_kernel<64><<<2048, 256, 0, stream>>>(G1, GdS, idx, 0, cat + 0, stats);
    fin_kernel<<<1, 64, 0, stream>>>(stats, 64, cntE, mean, invstd);
    apply_kernel<64><<<PTS*64/256, 256, 0, stream>>>(cat + 0, mean, invstd, g1, b1);

    // ---- Layer 2: C=64 -> O=64 ----
    sq_kernel<<<PTS/256, 256, 0, stream>>>(cat + 0, 512, 64, xx);
    xpose_kernel<64><<<dim3(16,1,32), 256, 0, stream>>>(cat + 0, 512, XT);
    knnf_kernel<64><<<dim3(64,32), 256, 0, stream>>>(cat + 0, 512, XT, xx, idx);
    hipMemsetAsync(stats, 0, 64*2*256*4, stream);
    gemmG_kernel<64,64><<<dim3(512,1), 256, 0, stream>>>(cat + 0, 512, W2, G1, GdS);
    gather_kernel<64><<<2048, 256, 0, stream>>>(G1, GdS, idx, 0, cat + 64, stats);
    fin_kernel<<<1, 64, 0, stream>>>(stats, 64, cntE, mean, invstd);
    apply_kernel<64><<<PTS*64/256, 256, 0, stream>>>(cat + 64, mean, invstd, g2, b2);

    // ---- Layer 3: C=64 -> O=128 ----
    sq_kernel<<<PTS/256, 256, 0, stream>>>(cat + 64, 512, 64, xx);
    xpose_kernel<64><<<dim3(16,1,32), 256, 0, stream>>>(cat + 64, 512, XT);
    knnf_kernel<64><<<dim3(64,32), 256, 0, stream>>>(cat + 64, 512, XT, xx, idx);
    hipMemsetAsync(stats, 0, 64*2*256*4, stream);
    gemmG_kernel<64,128><<<dim3(512,2), 256, 0, stream>>>(cat + 64, 512, W3, G1, GdS);
    gather_kernel<128><<<2048, 256, 0, stream>>>(G1, GdS, idx, 0, cat + 128, stats);
    fin_kernel<<<1, 128, 0, stream>>>(stats, 128, cntE, mean, invstd);
    apply_kernel<128><<<PTS*128/256, 256, 0, stream>>>(cat + 128, mean, invstd, g3, b3);

    // ---- Layer 4: C=128 -> O=256 ----
    sq_kernel<<<PTS/256, 256, 0, stream>>>(cat + 128, 512, 128, xx);
    xpose_kernel<128><<<dim3(16,2,32), 256, 0, stream>>>(cat + 128, 512, XT);
    knnf_kernel<128><<<dim3(64,32), 256, 0, stream>>>(cat + 128, 512, XT, xx, idx);
    hipMemsetAsync(stats, 0, 64*2*256*4, stream);
    if (bigG){
        gemmG_kernel<128,256><<<dim3(512,4), 256, 0, stream>>>(cat + 128, 512, W4, G1, GdB);
        gather_kernel<256><<<2048, 256, 0, stream>>>(G1, GdB, idx, 0, cat + 256, stats);
    } else {
        for (int bg = 0; bg < 4; ++bg){
            gemmG_kernel<128,256><<<dim3(128,4), 256, 0, stream>>>(cat + 128 + (size_t)bg*8192*512, 512, W4, G1, GdS);
            gather_kernel<256><<<512, 256, 0, stream>>>(G1, GdS, idx, bg*8192, cat + 256, stats);
        }
    }
    fin_kernel<<<1, 256, 0, stream>>>(stats, 256, cntE, mean, invstd);
    apply_kernel<256><<<PTS*256/256, 256, 0, stream>>>(cat + 256, mean, invstd, g4, b4);

    // ---- Layer 5: bf16 MFMA GEMM with fused max/stats ----
    tob16_kernel<<<PTS*512/4/256, 256, 0, stream>>>(cat, catB, PTS*512/4);
    tob16_kernel<<<1024*512/4/256, 256, 0, stream>>>(W5, W5b, 1024*512/4);
    l5m_kernel<<<dim3(256, 8), 256, 0, stream>>>(catB, W5b, pmax, psum, psq);
    fin5_kernel<<<4, 256, 0, stream>>>(pmax, psum, psq, g5, b5, out);
}